// Round 1
// baseline (376.660 us; speedup 1.0000x reference)
//
#include <hip/hip_runtime.h>

typedef unsigned short u16;
typedef __bf16 bf16x8 __attribute__((ext_vector_type(8)));
typedef float f32x4 __attribute__((ext_vector_type(4)));

#define T_   2048
#define C_   2048
#define HD_  128
#define NH_  16
#define NKV_ 4
#define M_   4096   // B*T

typedef __attribute__((address_space(1))) const void* as1_cvp;
typedef __attribute__((address_space(3))) void* as3_vp;

__device__ __forceinline__ void gload16(const void* g, void* l) {
  __builtin_amdgcn_global_load_lds((as1_cvp)g, (as3_vp)l, 16, 0, 0);
}

__device__ __forceinline__ u16 f2bf(float f) {
  unsigned u = __builtin_bit_cast(unsigned, f);
  return (u16)((u + 0x7fffu + ((u >> 16) & 1u)) >> 16);
}

// ---------------- fp32 -> bf16 plain convert ----------------
__global__ void cvt_bf16(const float4* __restrict__ in, ushort4* __restrict__ out, int n4) {
  int i = blockIdx.x * blockDim.x + threadIdx.x;
  if (i >= n4) return;
  float4 v = in[i];
  ushort4 r;
  r.x = f2bf(v.x); r.y = f2bf(v.y); r.z = f2bf(v.z); r.w = f2bf(v.w);
  out[i] = r;
}

// ---------------- RoPE folded into weight rows (angle indexed by HEAD, per reference quirk) ----
// W: [N][2048] fp32 row-major, rows j = h*128 + d; pair rows (2i, 2i+1).
__global__ void rope_fold_w(const float* __restrict__ W, u16* __restrict__ out, int npair) {
  int idx = blockIdx.x * blockDim.x + threadIdx.x;
  int p  = idx >> 9;            // pair index (512 col-chunks of 4 per pair)
  int c4 = (idx & 511) << 2;
  if (p >= npair) return;
  int h  = p >> 6;              // head index = (2p)>>7
  int ii = p & 63;              // dim-pair index within head
  float theta = __expf(-(float)ii * (9.210340371976184f / 64.0f)); // 10000^(-ii/64)
  float s, c;
  __sincosf((float)h * theta, &s, &c);
  size_t r0 = (size_t)(2 * p) * 2048 + c4;
  size_t r1 = r0 + 2048;
  float4 a = *(const float4*)(W + r0);
  float4 b = *(const float4*)(W + r1);
  ushort4 o0, o1;
  o0.x = f2bf(a.x * c - b.x * s); o0.y = f2bf(a.y * c - b.y * s);
  o0.z = f2bf(a.z * c - b.z * s); o0.w = f2bf(a.w * c - b.w * s);
  o1.x = f2bf(b.x * c + a.x * s); o1.y = f2bf(b.y * c + a.y * s);
  o1.z = f2bf(b.z * c + a.z * s); o1.w = f2bf(b.w * c + a.w * s);
  *(ushort4*)(out + r0) = o0;
  *(ushort4*)(out + r1) = o1;
}

__global__ void rope_fold_b(const float* __restrict__ bin, float* __restrict__ bout, int npair) {
  int p = blockIdx.x * blockDim.x + threadIdx.x;
  if (p >= npair) return;
  int h = p >> 6, ii = p & 63;
  float theta = __expf(-(float)ii * (9.210340371976184f / 64.0f));
  float s, c;
  __sincosf((float)h * theta, &s, &c);
  float a = bin[2 * p], b = bin[2 * p + 1];
  bout[2 * p]     = a * c - b * s;
  bout[2 * p + 1] = b * c + a * s;
}

// ---------------- GEMM: C[M,N] = A[M,K=2048] @ W[N,K]^T + bias ----------------
// MODE 0: out bf16 [B, H, T, HD] (QKV head-split layout)
// MODE 1: out fp32 row-major [M, N] (final projection -> d_out)
// MODE 2: out bf16 [B, H, HD, T] (V transposed for attention PV)
template<int MODE>
__global__ __launch_bounds__(256)
void gemm_bt(const u16* __restrict__ A, const u16* __restrict__ W,
             const float* __restrict__ bias, void* __restrict__ outp,
             const int N, const int H) {
  __shared__ __align__(16) u16 As[128 * 32];
  __shared__ __align__(16) u16 Bs[128 * 32];
  const int tid  = threadIdx.x;
  const int lane = tid & 63;
  const int wr = (tid >> 6) >> 1, wc = (tid >> 6) & 1;
  const int m0 = blockIdx.y << 7;
  const int n0 = blockIdx.x << 7;
  const int K = C_;

  const int srow = tid >> 2;
  const int scol = (tid & 3) << 3;
  const u16* gA = A + (size_t)(m0 + srow) * K + scol;
  const u16* gW = W + (size_t)(n0 + srow) * K + scol;
  u16* lA = &As[srow * 32 + scol];
  u16* lW = &Bs[srow * 32 + scol];

  const int fr = lane & 15;
  const int kg = (lane >> 4) << 3;

  f32x4 acc[4][4] = {};

  for (int k0 = 0; k0 < K; k0 += 32) {
    __syncthreads();
    gload16(gA + k0,               lA);
    gload16(gA + k0 + 64 * K,      lA + 64 * 32);
    gload16(gW + k0,               lW);
    gload16(gW + k0 + 64 * K,      lW + 64 * 32);
    __syncthreads();
    bf16x8 af[4], bq[4];
#pragma unroll
    for (int mi = 0; mi < 4; ++mi)
      af[mi] = *(const bf16x8*)&As[(wr * 64 + mi * 16 + fr) * 32 + kg];
#pragma unroll
    for (int ni = 0; ni < 4; ++ni)
      bq[ni] = *(const bf16x8*)&Bs[(wc * 64 + ni * 16 + fr) * 32 + kg];
#pragma unroll
    for (int mi = 0; mi < 4; ++mi)
#pragma unroll
      for (int ni = 0; ni < 4; ++ni)
        acc[mi][ni] = __builtin_amdgcn_mfma_f32_16x16x32_bf16(af[mi], bq[ni], acc[mi][ni], 0, 0, 0);
  }

  const int rbase = m0 + wr * 64 + ((lane >> 4) << 2);
#pragma unroll
  for (int ni = 0; ni < 4; ++ni) {
    const int cg = n0 + wc * 64 + ni * 16 + fr;
    const float bb = bias[cg];
#pragma unroll
    for (int mi = 0; mi < 4; ++mi) {
      const int rg0 = rbase + mi * 16;
#pragma unroll
      for (int r = 0; r < 4; ++r) {
        const float v = acc[mi][ni][r] + bb;
        const int rg = rg0 + r;
        if (MODE == 1) {
          ((float*)outp)[(size_t)rg * N + cg] = v;
        } else {
          const int b = rg >> 11, t = rg & (T_ - 1);
          const int h = cg >> 7, d = cg & (HD_ - 1);
          if (MODE == 0)
            ((u16*)outp)[((((size_t)b * H + h) * T_ + t) << 7) + d] = f2bf(v);
          else
            ((u16*)outp)[(((size_t)b * H + h) * HD_ + d) * T_ + t] = f2bf(v);
        }
      }
    }
  }
}

// ---------------- causal GQA flash attention ----------------
// q: [B,16,T,128] bf16, k: [B,4,T,128] bf16, vt: [B,4,128,T] bf16, y: [B,T,2048] bf16
__global__ __launch_bounds__(256)
void attn(const u16* __restrict__ q, const u16* __restrict__ k,
          const u16* __restrict__ vt, u16* __restrict__ y) {
  __shared__ __align__(16) u16 Qs[64 * 128];
  __shared__ __align__(16) u16 Ks[64 * 128];
  __shared__ __align__(16) u16 Vs[128 * 64];
  __shared__ __align__(16) u16 Ps[64 * 64];
  const int tid  = threadIdx.x;
  const int lane = tid & 63;
  const int wave = tid >> 6;
  const int qtile = blockIdx.x;
  const int h = blockIdx.y;
  const int b = blockIdx.z;
  const int q0 = qtile << 6;
  const size_t qbase = (((size_t)b * NH_ + h) * T_ + q0) * HD_;
  const size_t kbase = ((size_t)b * NKV_ + (h >> 2)) * (size_t)T_ * HD_;
  const size_t vbase = ((size_t)b * NKV_ + (h >> 2)) * (size_t)HD_ * T_;

  const int fr = lane & 15;
  const int kg = (lane >> 4) << 3;

  // stage Q (swizzled source -> linear LDS; reads XOR back)
  {
    const int r = tid >> 4, c8 = (tid & 15) << 3;
#pragma unroll
    for (int i = 0; i < 4; ++i) {
      const int row = i * 16 + r;
      gload16(q + qbase + (size_t)row * HD_ + (c8 ^ ((row & 7) << 3)), &Qs[row * 128 + c8]);
    }
  }
  __syncthreads();
  bf16x8 qf[4];
  {
    const int row = wave * 16 + fr;
#pragma unroll
    for (int kd = 0; kd < 4; ++kd)
      qf[kd] = *(const bf16x8*)&Qs[row * 128 + ((kd * 32 + kg) ^ ((row & 7) << 3))];
  }

  float m[4] = {-1e30f, -1e30f, -1e30f, -1e30f};
  float l[4] = {0.f, 0.f, 0.f, 0.f};
  f32x4 o[8] = {};

  for (int kv = 0; kv <= qtile; ++kv) {
    __syncthreads();
    {
      const int r = tid >> 4, c8 = (tid & 15) << 3;
#pragma unroll
      for (int i = 0; i < 4; ++i) {
        const int row = i * 16 + r;
        gload16(k + kbase + (size_t)((kv << 6) + row) * HD_ + (c8 ^ ((row & 7) << 3)),
                &Ks[row * 128 + c8]);
      }
      const int r2 = tid >> 3, c82 = (tid & 7) << 3;
#pragma unroll
      for (int i = 0; i < 4; ++i) {
        const int row = i * 32 + r2;
        gload16(vt + vbase + (size_t)row * T_ + (kv << 6) + (c82 ^ ((row & 7) << 3)),
                &Vs[row * 64 + c82]);
      }
    }
    __syncthreads();

    // S = Q @ K^T  (A = Q rows, B = K rows)
    f32x4 s[4] = {};
#pragma unroll
    for (int kj = 0; kj < 4; ++kj) {
      const int row = kj * 16 + fr;
#pragma unroll
      for (int kd = 0; kd < 4; ++kd) {
        bf16x8 kf = *(const bf16x8*)&Ks[row * 128 + ((kd * 32 + kg) ^ ((row & 7) << 3))];
        s[kj] = __builtin_amdgcn_mfma_f32_16x16x32_bf16(qf[kd], kf, s[kj], 0, 0, 0);
      }
    }

    const int qr0 = q0 + wave * 16 + ((lane >> 4) << 2);
    float p[4][4], tmax[4] = {-1e30f, -1e30f, -1e30f, -1e30f};
#pragma unroll
    for (int kj = 0; kj < 4; ++kj) {
      const int kt = (kv << 6) + kj * 16 + fr;
#pragma unroll
      for (int r = 0; r < 4; ++r) {
        float v = s[kj][r] * 0.08838834764831843f;   // 1/sqrt(128)
        if (kt > qr0 + r) v = -1e30f;
        p[kj][r] = v;
        tmax[r] = fmaxf(tmax[r], v);
      }
    }
#pragma unroll
    for (int r = 0; r < 4; ++r) {
      float t = tmax[r];
      t = fmaxf(t, __shfl_xor(t, 1));
      t = fmaxf(t, __shfl_xor(t, 2));
      t = fmaxf(t, __shfl_xor(t, 4));
      t = fmaxf(t, __shfl_xor(t, 8));
      tmax[r] = t;
    }
    float f[4], rs[4];
#pragma unroll
    for (int r = 0; r < 4; ++r) {
      const float mn = fmaxf(m[r], tmax[r]);
      f[r] = __expf(m[r] - mn);
      m[r] = mn;
      rs[r] = 0.f;
    }
#pragma unroll
    for (int kj = 0; kj < 4; ++kj) {
#pragma unroll
      for (int r = 0; r < 4; ++r) {
        const float pv = __expf(p[kj][r] - m[r]);
        rs[r] += pv;
        const int prow = wave * 16 + ((lane >> 4) << 2) + r;
        Ps[prow * 64 + ((kj * 16 + fr) ^ ((prow & 7) << 3))] = f2bf(pv);
      }
    }
#pragma unroll
    for (int r = 0; r < 4; ++r) {
      float t = rs[r];
      t += __shfl_xor(t, 1);
      t += __shfl_xor(t, 2);
      t += __shfl_xor(t, 4);
      t += __shfl_xor(t, 8);
      l[r] = l[r] * f[r] + t;
    }
#pragma unroll
    for (int d = 0; d < 8; ++d)
#pragma unroll
      for (int r = 0; r < 4; ++r) o[d][r] *= f[r];

    // O += P @ V   (A = P rows(q), B = Vt rows(d))
#pragma unroll
    for (int ks = 0; ks < 2; ++ks) {
      const int prow = wave * 16 + fr;
      bf16x8 pa = *(const bf16x8*)&Ps[prow * 64 + ((ks * 32 + kg) ^ ((prow & 7) << 3))];
#pragma unroll
      for (int d = 0; d < 8; ++d) {
        const int vrow = d * 16 + fr;
        bf16x8 vf = *(const bf16x8*)&Vs[vrow * 64 + ((ks * 32 + kg) ^ ((vrow & 7) << 3))];
        o[d] = __builtin_amdgcn_mfma_f32_16x16x32_bf16(pa, vf, o[d], 0, 0, 0);
      }
    }
  }

  const int t0 = q0 + wave * 16 + ((lane >> 4) << 2);
#pragma unroll
  for (int d = 0; d < 8; ++d) {
    const int c = (h << 7) + d * 16 + fr;
#pragma unroll
    for (int r = 0; r < 4; ++r)
      y[(size_t)((b << 11) + t0 + r) * C_ + c] = f2bf(o[d][r] / l[r]);
  }
}

// ---------------- launch ----------------
extern "C" void kernel_launch(void* const* d_in, const int* in_sizes, int n_in,
                              void* d_out, int out_size, void* d_ws, size_t ws_size,
                              hipStream_t stream) {
  (void)in_sizes; (void)n_in; (void)out_size; (void)ws_size;
  const float* x    = (const float*)d_in[0];
  const float* wq_w = (const float*)d_in[1];
  const float* wq_b = (const float*)d_in[2];
  const float* wk_w = (const float*)d_in[3];
  const float* wk_b = (const float*)d_in[4];
  const float* wv_w = (const float*)d_in[5];
  const float* wv_b = (const float*)d_in[6];
  const float* cp_w = (const float*)d_in[7];
  const float* cp_b = (const float*)d_in[8];

  char* ws = (char*)d_ws;
  u16* xb  = (u16*)ws;  ws += (size_t)M_ * C_ * 2;        // x bf16; later reused as y
  u16* wqr = (u16*)ws;  ws += (size_t)C_ * C_ * 2;        // rotated wq bf16
  u16* wkr = (u16*)ws;  ws += (size_t)512 * C_ * 2;       // rotated wk bf16
  u16* wvb = (u16*)ws;  ws += (size_t)512 * C_ * 2;       // wv bf16
  u16* cpb = (u16*)ws;  ws += (size_t)C_ * C_ * 2;        // cp bf16
  u16* qb  = (u16*)ws;  ws += (size_t)M_ * C_ * 2;        // q [B,16,T,128]
  u16* kb  = (u16*)ws;  ws += (size_t)M_ * 512 * 2;       // k [B,4,T,128]
  u16* vtb = (u16*)ws;  ws += (size_t)M_ * 512 * 2;       // v^T [B,4,128,T]
  float* bqr = (float*)ws; ws += 2048 * 4;                // rotated wq_b fp32
  float* bkr = (float*)ws; ws += 512 * 4;                 // rotated wk_b fp32
  u16* yb = xb;                                           // alias: x dead after V GEMM

  cvt_bf16<<<8192, 256, 0, stream>>>((const float4*)x,    (ushort4*)xb,  2097152);
  cvt_bf16<<<1024, 256, 0, stream>>>((const float4*)wv_w, (ushort4*)wvb, 262144);
  cvt_bf16<<<4096, 256, 0, stream>>>((const float4*)cp_w, (ushort4*)cpb, 1048576);
  rope_fold_w<<<2048, 256, 0, stream>>>(wq_w, wqr, 1024);
  rope_fold_w<<<512,  256, 0, stream>>>(wk_w, wkr, 256);
  rope_fold_b<<<4, 256, 0, stream>>>(wq_b, bqr, 1024);
  rope_fold_b<<<1, 256, 0, stream>>>(wk_b, bkr, 256);

  gemm_bt<0><<<dim3(16, 32), 256, 0, stream>>>(xb, wqr, bqr, qb,  2048, 16);
  gemm_bt<0><<<dim3(4,  32), 256, 0, stream>>>(xb, wkr, bkr, kb,  512,  4);
  gemm_bt<2><<<dim3(4,  32), 256, 0, stream>>>(xb, wvb, wv_b, vtb, 512, 4);

  attn<<<dim3(T_ / 64, NH_, 2), 256, 0, stream>>>(qb, kb, vtb, yb);

  gemm_bt<1><<<dim3(16, 32), 256, 0, stream>>>(yb, cpb, cp_b, (float*)d_out, 2048, 0);
}

// Round 2
// 281.414 us; speedup vs baseline: 1.3385x; 1.3385x over previous
//
#include <hip/hip_runtime.h>

typedef unsigned short u16;
typedef __bf16 bf16x8 __attribute__((ext_vector_type(8)));
typedef float f32x4 __attribute__((ext_vector_type(4)));
typedef float f32x16 __attribute__((ext_vector_type(16)));
typedef unsigned u32x4 __attribute__((ext_vector_type(4)));

#define T_   2048
#define C_   2048
#define HD_  128
#define NH_  16
#define NKV_ 4
#define M_   4096   // B*T

typedef __attribute__((address_space(1))) const void* as1_cvp;
typedef __attribute__((address_space(3))) void* as3_vp;

__device__ __forceinline__ void gload16(const void* g, void* l) {
  __builtin_amdgcn_global_load_lds((as1_cvp)g, (as3_vp)l, 16, 0, 0);
}

__device__ __forceinline__ u16 f2bf(float f) {
  unsigned u = __builtin_bit_cast(unsigned, f);
  return (u16)((u + 0x7fffu + ((u >> 16) & 1u)) >> 16);
}

__device__ __forceinline__ float fexp2(float x) {
  float r;
  asm("v_exp_f32 %0, %1" : "=v"(r) : "v"(x));
  return r;
}

__device__ __forceinline__ unsigned cvtpk(float a, float b) {
  unsigned d;
  asm("v_cvt_pk_bf16_f32 %0, %1, %2" : "=v"(d) : "v"(a), "v"(b));
  return d;
}

// ---------------- fp32 -> bf16 plain convert ----------------
__global__ void cvt_bf16(const float4* __restrict__ in, ushort4* __restrict__ out, int n4) {
  int i = blockIdx.x * blockDim.x + threadIdx.x;
  if (i >= n4) return;
  float4 v = in[i];
  ushort4 r;
  r.x = f2bf(v.x); r.y = f2bf(v.y); r.z = f2bf(v.z); r.w = f2bf(v.w);
  out[i] = r;
}

// ---------------- RoPE folded into weight rows (angle indexed by HEAD, per reference quirk) ----
__global__ void rope_fold_w(const float* __restrict__ W, u16* __restrict__ out, int npair) {
  int idx = blockIdx.x * blockDim.x + threadIdx.x;
  int p  = idx >> 9;
  int c4 = (idx & 511) << 2;
  if (p >= npair) return;
  int h  = p >> 6;
  int ii = p & 63;
  float theta = __expf(-(float)ii * (9.210340371976184f / 64.0f));
  float s, c;
  __sincosf((float)h * theta, &s, &c);
  size_t r0 = (size_t)(2 * p) * 2048 + c4;
  size_t r1 = r0 + 2048;
  float4 a = *(const float4*)(W + r0);
  float4 b = *(const float4*)(W + r1);
  ushort4 o0, o1;
  o0.x = f2bf(a.x * c - b.x * s); o0.y = f2bf(a.y * c - b.y * s);
  o0.z = f2bf(a.z * c - b.z * s); o0.w = f2bf(a.w * c - b.w * s);
  o1.x = f2bf(b.x * c + a.x * s); o1.y = f2bf(b.y * c + a.y * s);
  o1.z = f2bf(b.z * c + a.z * s); o1.w = f2bf(b.w * c + a.w * s);
  *(ushort4*)(out + r0) = o0;
  *(ushort4*)(out + r1) = o1;
}

__global__ void rope_fold_b(const float* __restrict__ bin, float* __restrict__ bout, int npair) {
  int p = blockIdx.x * blockDim.x + threadIdx.x;
  if (p >= npair) return;
  int h = p >> 6, ii = p & 63;
  float theta = __expf(-(float)ii * (9.210340371976184f / 64.0f));
  float s, c;
  __sincosf((float)h * theta, &s, &c);
  float a = bin[2 * p], b = bin[2 * p + 1];
  bout[2 * p]     = a * c - b * s;
  bout[2 * p + 1] = b * c + a * s;
}

// ---------------- GEMM: C[M,N] = A[M,K=2048] @ W[N,K]^T + bias ----------------
// MODE 0: out bf16 [B, H, T, HD];  MODE 1: out fp32 [M, N];  MODE 2: out bf16 [B, H, HD, T]
template<int MODE>
__global__ __launch_bounds__(256)
void gemm_bt(const u16* __restrict__ A, const u16* __restrict__ W,
             const float* __restrict__ bias, void* __restrict__ outp,
             const int N, const int H, const float scale) {
  __shared__ __align__(16) u16 As[128 * 32];
  __shared__ __align__(16) u16 Bs[128 * 32];
  const int tid  = threadIdx.x;
  const int lane = tid & 63;
  const int wr = (tid >> 6) >> 1, wc = (tid >> 6) & 1;
  const int m0 = blockIdx.y << 7;
  const int n0 = blockIdx.x << 7;
  const int K = C_;

  const int srow = tid >> 2;
  const int scol = (tid & 3) << 3;
  const u16* gA = A + (size_t)(m0 + srow) * K + scol;
  const u16* gW = W + (size_t)(n0 + srow) * K + scol;
  u16* lA = &As[srow * 32 + scol];
  u16* lW = &Bs[srow * 32 + scol];

  const int fr = lane & 15;
  const int kg = (lane >> 4) << 3;

  f32x4 acc[4][4] = {};

  for (int k0 = 0; k0 < K; k0 += 32) {
    __syncthreads();
    gload16(gA + k0,               lA);
    gload16(gA + k0 + 64 * K,      lA + 64 * 32);
    gload16(gW + k0,               lW);
    gload16(gW + k0 + 64 * K,      lW + 64 * 32);
    __syncthreads();
    bf16x8 af[4], bq[4];
#pragma unroll
    for (int mi = 0; mi < 4; ++mi)
      af[mi] = *(const bf16x8*)&As[(wr * 64 + mi * 16 + fr) * 32 + kg];
#pragma unroll
    for (int ni = 0; ni < 4; ++ni)
      bq[ni] = *(const bf16x8*)&Bs[(wc * 64 + ni * 16 + fr) * 32 + kg];
#pragma unroll
    for (int mi = 0; mi < 4; ++mi)
#pragma unroll
      for (int ni = 0; ni < 4; ++ni)
        acc[mi][ni] = __builtin_amdgcn_mfma_f32_16x16x32_bf16(af[mi], bq[ni], acc[mi][ni], 0, 0, 0);
  }

  const int rbase = m0 + wr * 64 + ((lane >> 4) << 2);
#pragma unroll
  for (int ni = 0; ni < 4; ++ni) {
    const int cg = n0 + wc * 64 + ni * 16 + fr;
    const float bb = bias[cg];
#pragma unroll
    for (int mi = 0; mi < 4; ++mi) {
      const int rg0 = rbase + mi * 16;
#pragma unroll
      for (int r = 0; r < 4; ++r) {
        const float v = (acc[mi][ni][r] + bb) * scale;
        const int rg = rg0 + r;
        if (MODE == 1) {
          ((float*)outp)[(size_t)rg * N + cg] = v;
        } else {
          const int b = rg >> 11, t = rg & (T_ - 1);
          const int h = cg >> 7, d = cg & (HD_ - 1);
          if (MODE == 0)
            ((u16*)outp)[((((size_t)b * H + h) * T_ + t) << 7) + d] = f2bf(v);
          else
            ((u16*)outp)[(((size_t)b * H + h) * HD_ + d) * T_ + t] = f2bf(v);
        }
      }
    }
  }
}

// ---------------- causal GQA flash attention (4 warps x 32 q-rows, 32x32x16 MFMA) ------------
// q: [B,16,T,128] bf16 (pre-scaled by log2e/sqrt(128)), k: [B,4,T,128] bf16,
// vt: [B,4,128,T] bf16, y: [B,T,2048] bf16
// LDS layout (u16 idx): buf b at b*16384: K tile [64][128] at +0, Vt tile [128][64] at +8192.
// 16B-chunk XOR swizzle: chunk ^= (row&7); applied via pre-swizzled global source (rule #21).
__device__ __forceinline__ void stage_kv(u16* dst, const u16* __restrict__ kg,
                                         const u16* __restrict__ vg, int lane, int w) {
#pragma unroll
  for (int r = 0; r < 4; ++r) {           // K: 64 rows x 16 chunks
    const int row = r * 16 + w * 4 + (lane >> 4);
    const int cg  = (lane & 15) ^ (row & 7);
    gload16(kg + (size_t)row * 128 + cg * 8, dst + row * 128 + (lane & 15) * 8);
  }
#pragma unroll
  for (int r = 0; r < 4; ++r) {           // Vt: 128 rows x 8 chunks
    const int row = r * 32 + w * 8 + (lane >> 3);
    const int cg  = (lane & 7) ^ (row & 7);
    gload16(vg + (size_t)row * T_ + cg * 8, dst + 8192 + row * 64 + (lane & 7) * 8);
  }
}

__global__ __launch_bounds__(256, 2)
void attn2(const u16* __restrict__ q, const u16* __restrict__ k,
           const u16* __restrict__ vt, u16* __restrict__ y) {
  __shared__ __align__(16) u16 sm[32768];
  const int tid  = threadIdx.x;
  const int lane = tid & 63;
  const int w    = tid >> 6;
  const int hi   = lane >> 5;
  const int l5   = lane & 31;
  const int qt = (int)gridDim.x - 1 - (int)blockIdx.x;   // longest blocks first
  const int h = blockIdx.y;
  const int b = blockIdx.z;
  const int q0  = qt << 7;
  const int q0w = q0 + w * 32;
  const int nkv = 2 * qt + 2;
  const size_t qbase = (((size_t)b * NH_ + h) * T_ + q0) * HD_;
  const size_t kbase = ((size_t)b * NKV_ + (h >> 2)) * (size_t)T_ * HD_;
  const size_t vbase = ((size_t)b * NKV_ + (h >> 2)) * (size_t)HD_ * T_;

  // ---- stage Q [128][128] (swizzled) into sm[0..16384)
#pragma unroll
  for (int r = 0; r < 8; ++r) {
    const int row = r * 16 + w * 4 + (lane >> 4);
    const int cg  = (lane & 15) ^ (row & 7);
    gload16(q + qbase + (size_t)row * 128 + cg * 8, sm + row * 128 + (lane & 15) * 8);
  }
  __syncthreads();
  bf16x8 qf[8];
  {
    const int row = w * 32 + l5;
#pragma unroll
    for (int kd = 0; kd < 8; ++kd)
      qf[kd] = *(const bf16x8*)&sm[row * 128 + ((((kd << 1) | hi) ^ (row & 7)) << 3)];
  }
  __syncthreads();
  stage_kv(sm, k + kbase, vt + vbase, lane, w);

  f32x16 o[4] = {};
  float m = -1e30f, l = 0.f;

  for (int kv = 0; kv < nkv; ++kv) {
    __syncthreads();               // staging of current buf complete (vmcnt(0)+barrier)
    const int buf = kv & 1;
    if (kv + 1 < nkv)
      stage_kv(sm + ((buf ^ 1) << 14),
               k + kbase + ((size_t)(kv + 1) << 6) * 128,
               vt + vbase + ((kv + 1) << 6), lane, w);

    if ((kv << 6) <= q0w + 31) {
      const u16* Ks = sm + (buf << 14);
      const u16* Vs = Ks + 8192;

      // ---- S^T = K @ Q^T : lane holds S^T[k=crow(r,hi)][q=l5]
      f32x16 st[2] = {};
#pragma unroll
      for (int kt = 0; kt < 2; ++kt) {
        const int krow = kt * 32 + l5;
#pragma unroll
        for (int kd = 0; kd < 8; ++kd) {
          bf16x8 ka = *(const bf16x8*)&Ks[krow * 128 + ((((kd << 1) | hi) ^ (l5 & 7)) << 3)];
          st[kt] = __builtin_amdgcn_mfma_f32_32x32x16_bf16(ka, qf[kd], st[kt], 0, 0, 0);
        }
      }

      // ---- causal mask (diagonal tiles only)
      if ((kv << 6) + 63 > q0w) {
        const int qg = q0w + l5;
#pragma unroll
        for (int kt = 0; kt < 2; ++kt)
#pragma unroll
          for (int r = 0; r < 16; ++r) {
            const int kg = (kv << 6) + kt * 32 + (r & 3) + ((r >> 2) << 3) + (hi << 2);
            if (kg > qg) st[kt][r] = -3.0e38f;
          }
      }

      // ---- online softmax (log2 domain; scale folded into Q)
      float pmax = -3.0e38f;
#pragma unroll
      for (int kt = 0; kt < 2; ++kt)
#pragma unroll
        for (int r = 0; r < 16; ++r) pmax = fmaxf(pmax, st[kt][r]);
      pmax = fmaxf(pmax, __shfl_xor(pmax, 32));
      if (!__all(pmax - m <= 8.0f)) {        // defer-max (T13)
        const float mn = fmaxf(m, pmax);
        const float f = fexp2(m - mn);
        m = mn;
        l *= f;
#pragma unroll
        for (int r = 0; r < 16; ++r) {
          const float fr = __shfl(f, (r & 3) + ((r >> 2) << 3) + (hi << 2));
          o[0][r] *= fr; o[1][r] *= fr; o[2][r] *= fr; o[3][r] *= fr;
        }
      }

      // ---- P = exp2(S^T - m), pack to PV A-fragments in-register, PV MFMAs
      float rs = 0.f;
#pragma unroll
      for (int kt = 0; kt < 2; ++kt) {
#pragma unroll
        for (int s = 0; s < 2; ++s) {
          float e0 = fexp2(st[kt][8 * s + 0] - m), e1 = fexp2(st[kt][8 * s + 1] - m);
          float e2 = fexp2(st[kt][8 * s + 2] - m), e3 = fexp2(st[kt][8 * s + 3] - m);
          float e4 = fexp2(st[kt][8 * s + 4] - m), e5 = fexp2(st[kt][8 * s + 5] - m);
          float e6 = fexp2(st[kt][8 * s + 6] - m), e7 = fexp2(st[kt][8 * s + 7] - m);
          rs += ((e0 + e1) + (e2 + e3)) + ((e4 + e5) + (e6 + e7));
          const unsigned wL0 = cvtpk(e0, e1), wL1 = cvtpk(e2, e3);
          const unsigned wH0 = cvtpk(e4, e5), wH1 = cvtpk(e6, e7);
          const unsigned s0 = hi ? wL0 : wH0, s1 = hi ? wL1 : wH1;
          const unsigned r0 = __shfl_xor(s0, 32), r1 = __shfl_xor(s1, 32);
          u32x4 fw;
          fw.x = hi ? r0 : wL0; fw.y = hi ? r1 : wL1;
          fw.z = hi ? wH0 : r0; fw.w = hi ? wH1 : r1;
          const bf16x8 pa = __builtin_bit_cast(bf16x8, fw);
          const int ch = (((kt * 2 + s) << 1) | hi) ^ (l5 & 7);
#pragma unroll
          for (int ds = 0; ds < 4; ++ds) {
            const int vrow = ds * 32 + l5;
            bf16x8 vb = *(const bf16x8*)&Vs[vrow * 64 + (ch << 3)];
            o[ds] = __builtin_amdgcn_mfma_f32_32x32x16_bf16(pa, vb, o[ds], 0, 0, 0);
          }
        }
      }
      rs += __shfl_xor(rs, 32);
      l += rs;
    }
  }

  // ---- epilogue: O /= l, write y[b, q, h*128 + d]
  const float linv = 1.0f / l;
#pragma unroll
  for (int r = 0; r < 16; ++r) {
    const int crow = (r & 3) + ((r >> 2) << 3) + (hi << 2);
    const float lf = __shfl(linv, crow);
    const int qg = q0w + crow;
    const size_t rowoff = (((size_t)(b << 11) + qg) << 11) + (h << 7) + l5;
#pragma unroll
    for (int ds = 0; ds < 4; ++ds)
      y[rowoff + ds * 32] = f2bf(o[ds][r] * lf);
  }
}

// ---------------- launch ----------------
extern "C" void kernel_launch(void* const* d_in, const int* in_sizes, int n_in,
                              void* d_out, int out_size, void* d_ws, size_t ws_size,
                              hipStream_t stream) {
  (void)in_sizes; (void)n_in; (void)out_size; (void)ws_size;
  const float* x    = (const float*)d_in[0];
  const float* wq_w = (const float*)d_in[1];
  const float* wq_b = (const float*)d_in[2];
  const float* wk_w = (const float*)d_in[3];
  const float* wk_b = (const float*)d_in[4];
  const float* wv_w = (const float*)d_in[5];
  const float* wv_b = (const float*)d_in[6];
  const float* cp_w = (const float*)d_in[7];
  const float* cp_b = (const float*)d_in[8];

  char* ws = (char*)d_ws;
  u16* xb  = (u16*)ws;  ws += (size_t)M_ * C_ * 2;
  u16* wqr = (u16*)ws;  ws += (size_t)C_ * C_ * 2;
  u16* wkr = (u16*)ws;  ws += (size_t)512 * C_ * 2;
  u16* wvb = (u16*)ws;  ws += (size_t)512 * C_ * 2;
  u16* cpb = (u16*)ws;  ws += (size_t)C_ * C_ * 2;
  u16* qb  = (u16*)ws;  ws += (size_t)M_ * C_ * 2;
  u16* kb  = (u16*)ws;  ws += (size_t)M_ * 512 * 2;
  u16* vtb = (u16*)ws;  ws += (size_t)M_ * 512 * 2;
  float* bqr = (float*)ws; ws += 2048 * 4;
  float* bkr = (float*)ws; ws += 512 * 4;
  u16* yb = xb;

  cvt_bf16<<<8192, 256, 0, stream>>>((const float4*)x,    (ushort4*)xb,  2097152);
  cvt_bf16<<<1024, 256, 0, stream>>>((const float4*)wv_w, (ushort4*)wvb, 262144);
  cvt_bf16<<<4096, 256, 0, stream>>>((const float4*)cp_w, (ushort4*)cpb, 1048576);
  rope_fold_w<<<2048, 256, 0, stream>>>(wq_w, wqr, 1024);
  rope_fold_w<<<512,  256, 0, stream>>>(wk_w, wkr, 256);
  rope_fold_b<<<4, 256, 0, stream>>>(wq_b, bqr, 1024);
  rope_fold_b<<<1, 256, 0, stream>>>(wk_b, bkr, 256);

  // Q pre-scaled by log2e / sqrt(HD) so attention softmax runs in exp2 domain
  const float qscale = 0.08838834764831843f * 1.4426950408889634f;
  gemm_bt<0><<<dim3(16, 32), 256, 0, stream>>>(xb, wqr, bqr, qb,  2048, 16, qscale);
  gemm_bt<0><<<dim3(4,  32), 256, 0, stream>>>(xb, wkr, bkr, kb,  512,  4, 1.0f);
  gemm_bt<2><<<dim3(4,  32), 256, 0, stream>>>(xb, wvb, wv_b, vtb, 512, 4, 1.0f);

  attn2<<<dim3(16, 16, 2), 256, 0, stream>>>(qb, kb, vtb, yb);

  gemm_bt<1><<<dim3(16, 32), 256, 0, stream>>>(yb, cpb, cp_b, (float*)d_out, 2048, 0, 1.0f);
}

// Round 3
// 236.859 us; speedup vs baseline: 1.5902x; 1.1881x over previous
//
#include <hip/hip_runtime.h>

typedef unsigned short u16;
typedef __bf16 bf16x8 __attribute__((ext_vector_type(8)));
typedef float f32x4 __attribute__((ext_vector_type(4)));
typedef float f32x16 __attribute__((ext_vector_type(16)));
typedef unsigned u32x4 __attribute__((ext_vector_type(4)));

#define T_   2048
#define C_   2048
#define HD_  128
#define NH_  16
#define NKV_ 4
#define M_   4096   // B*T

typedef __attribute__((address_space(1))) const void* as1_cvp;
typedef __attribute__((address_space(3))) void* as3_vp;

__device__ __forceinline__ void gload16(const void* g, void* l) {
  __builtin_amdgcn_global_load_lds((as1_cvp)g, (as3_vp)l, 16, 0, 0);
}

__device__ __forceinline__ u16 f2bf(float f) {
  unsigned u = __builtin_bit_cast(unsigned, f);
  return (u16)((u + 0x7fffu + ((u >> 16) & 1u)) >> 16);
}

__device__ __forceinline__ float fexp2(float x) {
  float r;
  asm("v_exp_f32 %0, %1" : "=v"(r) : "v"(x));
  return r;
}

__device__ __forceinline__ unsigned cvtpk(float a, float b) {
  unsigned d;
  asm("v_cvt_pk_bf16_f32 %0, %1, %2" : "=v"(d) : "v"(a), "v"(b));
  return d;
}

// ---------------- fp32 -> bf16 plain convert ----------------
__global__ void cvt_bf16(const float4* __restrict__ in, ushort4* __restrict__ out, int n4) {
  int i = blockIdx.x * blockDim.x + threadIdx.x;
  if (i >= n4) return;
  float4 v = in[i];
  ushort4 r;
  r.x = f2bf(v.x); r.y = f2bf(v.y); r.z = f2bf(v.z); r.w = f2bf(v.w);
  out[i] = r;
}

__global__ void copy_f32(const float* __restrict__ in, float* __restrict__ out, int n) {
  int i = blockIdx.x * blockDim.x + threadIdx.x;
  if (i < n) out[i] = in[i];
}

// ---------------- RoPE folded into weight rows (angle indexed by HEAD, per reference quirk) ----
__global__ void rope_fold_w(const float* __restrict__ W, u16* __restrict__ out, int npair) {
  int idx = blockIdx.x * blockDim.x + threadIdx.x;
  int p  = idx >> 9;
  int c4 = (idx & 511) << 2;
  if (p >= npair) return;
  int h  = p >> 6;
  int ii = p & 63;
  float theta = __expf(-(float)ii * (9.210340371976184f / 64.0f));
  float s, c;
  __sincosf((float)h * theta, &s, &c);
  size_t r0 = (size_t)(2 * p) * 2048 + c4;
  size_t r1 = r0 + 2048;
  float4 a = *(const float4*)(W + r0);
  float4 b = *(const float4*)(W + r1);
  ushort4 o0, o1;
  o0.x = f2bf(a.x * c - b.x * s); o0.y = f2bf(a.y * c - b.y * s);
  o0.z = f2bf(a.z * c - b.z * s); o0.w = f2bf(a.w * c - b.w * s);
  o1.x = f2bf(b.x * c + a.x * s); o1.y = f2bf(b.y * c + a.y * s);
  o1.z = f2bf(b.z * c + a.z * s); o1.w = f2bf(b.w * c + a.w * s);
  *(ushort4*)(out + r0) = o0;
  *(ushort4*)(out + r1) = o1;
}

__global__ void rope_fold_b(const float* __restrict__ bin, float* __restrict__ bout, int npair) {
  int p = blockIdx.x * blockDim.x + threadIdx.x;
  if (p >= npair) return;
  int h = p >> 6, ii = p & 63;
  float theta = __expf(-(float)ii * (9.210340371976184f / 64.0f));
  float s, c;
  __sincosf((float)h * theta, &s, &c);
  float a = bin[2 * p], b = bin[2 * p + 1];
  bout[2 * p]     = a * c - b * s;
  bout[2 * p + 1] = b * c + a * s;
}

// ---------------- fused QKV GEMM: [M,3072] = A[M,2048] @ Wcat[3072,2048]^T + bias ----------
// cols [0,2048): Q -> qb [B,16,T,128] scaled by qscale; [2048,2560): K -> kb [B,4,T,128];
// [2560,3072): V -> vtb [B,4,128,T] (transposed).
__global__ __launch_bounds__(256)
void gemm_qkv(const u16* __restrict__ A, const u16* __restrict__ W,
              const float* __restrict__ bias, u16* __restrict__ qo,
              u16* __restrict__ ko, u16* __restrict__ vo, const float qscale) {
  __shared__ __align__(16) u16 As[128 * 32];
  __shared__ __align__(16) u16 Bs[128 * 32];
  const int tid  = threadIdx.x;
  const int lane = tid & 63;
  const int wr = (tid >> 6) >> 1, wc = (tid >> 6) & 1;
  const int m0 = blockIdx.y << 7;
  const int n0 = blockIdx.x << 7;
  const int K = C_;

  const int srow = tid >> 2;
  const int scol = (tid & 3) << 3;
  const u16* gA = A + (size_t)(m0 + srow) * K + scol;
  const u16* gW = W + (size_t)(n0 + srow) * K + scol;
  u16* lA = &As[srow * 32 + scol];
  u16* lW = &Bs[srow * 32 + scol];

  const int fr = lane & 15;
  const int kg = (lane >> 4) << 3;

  f32x4 acc[4][4] = {};

  for (int k0 = 0; k0 < K; k0 += 32) {
    __syncthreads();
    gload16(gA + k0,               lA);
    gload16(gA + k0 + 64 * K,      lA + 64 * 32);
    gload16(gW + k0,               lW);
    gload16(gW + k0 + 64 * K,      lW + 64 * 32);
    __syncthreads();
    bf16x8 af[4], bq[4];
#pragma unroll
    for (int mi = 0; mi < 4; ++mi)
      af[mi] = *(const bf16x8*)&As[(wr * 64 + mi * 16 + fr) * 32 + kg];
#pragma unroll
    for (int ni = 0; ni < 4; ++ni)
      bq[ni] = *(const bf16x8*)&Bs[(wc * 64 + ni * 16 + fr) * 32 + kg];
#pragma unroll
    for (int mi = 0; mi < 4; ++mi)
#pragma unroll
      for (int ni = 0; ni < 4; ++ni)
        acc[mi][ni] = __builtin_amdgcn_mfma_f32_16x16x32_bf16(af[mi], bq[ni], acc[mi][ni], 0, 0, 0);
  }

  const int rbase = m0 + wr * 64 + ((lane >> 4) << 2);
#pragma unroll
  for (int ni = 0; ni < 4; ++ni) {
    const int cg = n0 + wc * 64 + ni * 16 + fr;
    const float bb = bias[cg];
#pragma unroll
    for (int mi = 0; mi < 4; ++mi) {
      const int rg0 = rbase + mi * 16;
#pragma unroll
      for (int r = 0; r < 4; ++r) {
        float v = acc[mi][ni][r] + bb;
        const int rg = rg0 + r;
        const int b = rg >> 11, t = rg & (T_ - 1);
        if (n0 < 2048) {
          const int h = cg >> 7, d = cg & 127;
          qo[((((size_t)b * NH_ + h) * T_ + t) << 7) + d] = f2bf(v * qscale);
        } else if (n0 < 2560) {
          const int c2 = cg - 2048, h = c2 >> 7, d = c2 & 127;
          ko[((((size_t)b * NKV_ + h) * T_ + t) << 7) + d] = f2bf(v);
        } else {
          const int c2 = cg - 2560, h = c2 >> 7, d = c2 & 127;
          vo[(((size_t)b * NKV_ + h) * HD_ + d) * T_ + t] = f2bf(v);
        }
      }
    }
  }
}

// ---------------- final projection GEMM: out fp32 [M, N] ----------------
__global__ __launch_bounds__(256)
void gemm_proj(const u16* __restrict__ A, const u16* __restrict__ W,
               const float* __restrict__ bias, float* __restrict__ outp, const int N) {
  __shared__ __align__(16) u16 As[128 * 32];
  __shared__ __align__(16) u16 Bs[128 * 32];
  const int tid  = threadIdx.x;
  const int lane = tid & 63;
  const int wr = (tid >> 6) >> 1, wc = (tid >> 6) & 1;
  const int m0 = blockIdx.y << 7;
  const int n0 = blockIdx.x << 7;
  const int K = C_;

  const int srow = tid >> 2;
  const int scol = (tid & 3) << 3;
  const u16* gA = A + (size_t)(m0 + srow) * K + scol;
  const u16* gW = W + (size_t)(n0 + srow) * K + scol;
  u16* lA = &As[srow * 32 + scol];
  u16* lW = &Bs[srow * 32 + scol];

  const int fr = lane & 15;
  const int kg = (lane >> 4) << 3;

  f32x4 acc[4][4] = {};

  for (int k0 = 0; k0 < K; k0 += 32) {
    __syncthreads();
    gload16(gA + k0,               lA);
    gload16(gA + k0 + 64 * K,      lA + 64 * 32);
    gload16(gW + k0,               lW);
    gload16(gW + k0 + 64 * K,      lW + 64 * 32);
    __syncthreads();
    bf16x8 af[4], bq[4];
#pragma unroll
    for (int mi = 0; mi < 4; ++mi)
      af[mi] = *(const bf16x8*)&As[(wr * 64 + mi * 16 + fr) * 32 + kg];
#pragma unroll
    for (int ni = 0; ni < 4; ++ni)
      bq[ni] = *(const bf16x8*)&Bs[(wc * 64 + ni * 16 + fr) * 32 + kg];
#pragma unroll
    for (int mi = 0; mi < 4; ++mi)
#pragma unroll
      for (int ni = 0; ni < 4; ++ni)
        acc[mi][ni] = __builtin_amdgcn_mfma_f32_16x16x32_bf16(af[mi], bq[ni], acc[mi][ni], 0, 0, 0);
  }

  const int rbase = m0 + wr * 64 + ((lane >> 4) << 2);
#pragma unroll
  for (int ni = 0; ni < 4; ++ni) {
    const int cg = n0 + wc * 64 + ni * 16 + fr;
    const float bb = bias[cg];
#pragma unroll
    for (int mi = 0; mi < 4; ++mi) {
      const int rg0 = rbase + mi * 16;
#pragma unroll
      for (int r = 0; r < 4; ++r)
        outp[(size_t)(rg0 + r) * N + cg] = acc[mi][ni][r] + bb;
    }
  }
}

// ---------------- causal GQA flash attention (4 warps x 32 q-rows, 32x32x16 MFMA) ------------
__device__ __forceinline__ void stage_kv(u16* dst, const u16* __restrict__ kg,
                                         const u16* __restrict__ vg, int lane, int w) {
#pragma unroll
  for (int r = 0; r < 4; ++r) {           // K: 64 rows x 16 chunks
    const int row = r * 16 + w * 4 + (lane >> 4);
    const int cg  = (lane & 15) ^ (row & 7);
    gload16(kg + (size_t)row * 128 + cg * 8, dst + row * 128 + (lane & 15) * 8);
  }
#pragma unroll
  for (int r = 0; r < 4; ++r) {           // Vt: 128 rows x 8 chunks
    const int row = r * 32 + w * 8 + (lane >> 3);
    const int cg  = (lane & 7) ^ (row & 7);
    gload16(vg + (size_t)row * T_ + cg * 8, dst + 8192 + row * 64 + (lane & 7) * 8);
  }
}

__global__ __launch_bounds__(256, 2)
void attn2(const u16* __restrict__ q, const u16* __restrict__ k,
           const u16* __restrict__ vt, u16* __restrict__ y) {
  __shared__ __align__(16) u16 sm[32768];
  const int tid  = threadIdx.x;
  const int lane = tid & 63;
  const int w    = tid >> 6;
  const int hi   = lane >> 5;
  const int l5   = lane & 31;
  const int h = blockIdx.y;
  const int b = blockIdx.z;
  // complementary pairing: co-resident (x,y,0)/(x,y,1) get qt summing to 15 -> uniform CU load
  const int qt = b ? (int)blockIdx.x : (15 - (int)blockIdx.x);
  const int q0  = qt << 7;
  const int q0w = q0 + w * 32;
  const int nkv = 2 * qt + 2;
  const size_t qbase = (((size_t)b * NH_ + h) * T_ + q0) * HD_;
  const size_t kbase = ((size_t)b * NKV_ + (h >> 2)) * (size_t)T_ * HD_;
  const size_t vbase = ((size_t)b * NKV_ + (h >> 2)) * (size_t)HD_ * T_;

  // ---- stage Q [128][128] (swizzled) into sm[0..16384)
#pragma unroll
  for (int r = 0; r < 8; ++r) {
    const int row = r * 16 + w * 4 + (lane >> 4);
    const int cg  = (lane & 15) ^ (row & 7);
    gload16(q + qbase + (size_t)row * 128 + cg * 8, sm + row * 128 + (lane & 15) * 8);
  }
  __syncthreads();
  bf16x8 qf[8];
  {
    const int row = w * 32 + l5;
#pragma unroll
    for (int kd = 0; kd < 8; ++kd)
      qf[kd] = *(const bf16x8*)&sm[row * 128 + ((((kd << 1) | hi) ^ (row & 7)) << 3)];
  }
  __syncthreads();
  stage_kv(sm, k + kbase, vt + vbase, lane, w);

  f32x16 o[4] = {};
  float m = -1e30f, l = 0.f;

  for (int kv = 0; kv < nkv; ++kv) {
    __syncthreads();               // staging of current buf complete (vmcnt(0)+barrier)
    const int buf = kv & 1;
    if (kv + 1 < nkv)
      stage_kv(sm + ((buf ^ 1) << 14),
               k + kbase + ((size_t)(kv + 1) << 6) * 128,
               vt + vbase + ((kv + 1) << 6), lane, w);

    if ((kv << 6) <= q0w + 31) {
      const u16* Ks = sm + (buf << 14);
      const u16* Vs = Ks + 8192;

      // ---- S^T = K @ Q^T : lane holds S^T[k=crow(r,hi)][q=l5]
      f32x16 st[2] = {};
      __builtin_amdgcn_s_setprio(1);
#pragma unroll
      for (int kt = 0; kt < 2; ++kt) {
        const int krow = kt * 32 + l5;
#pragma unroll
        for (int kd = 0; kd < 8; ++kd) {
          bf16x8 ka = *(const bf16x8*)&Ks[krow * 128 + ((((kd << 1) | hi) ^ (l5 & 7)) << 3)];
          st[kt] = __builtin_amdgcn_mfma_f32_32x32x16_bf16(ka, qf[kd], st[kt], 0, 0, 0);
        }
      }
      __builtin_amdgcn_s_setprio(0);

      // ---- causal mask (diagonal tiles only)
      if ((kv << 6) + 63 > q0w) {
        const int qg = q0w + l5;
#pragma unroll
        for (int kt = 0; kt < 2; ++kt)
#pragma unroll
          for (int r = 0; r < 16; ++r) {
            const int kg = (kv << 6) + kt * 32 + (r & 3) + ((r >> 2) << 3) + (hi << 2);
            if (kg > qg) st[kt][r] = -3.0e38f;
          }
      }

      // ---- online softmax (log2 domain; scale folded into Q)
      float pmax = -3.0e38f;
#pragma unroll
      for (int kt = 0; kt < 2; ++kt)
#pragma unroll
        for (int r = 0; r < 16; ++r) pmax = fmaxf(pmax, st[kt][r]);
      pmax = fmaxf(pmax, __shfl_xor(pmax, 32));
      if (!__all(pmax - m <= 8.0f)) {        // defer-max (T13)
        const float mn = fmaxf(m, pmax);
        const float f = fexp2(m - mn);
        m = mn;
        l *= f;
#pragma unroll
        for (int r = 0; r < 16; ++r) {
          const float fr = __shfl(f, (r & 3) + ((r >> 2) << 3) + (hi << 2));
          o[0][r] *= fr; o[1][r] *= fr; o[2][r] *= fr; o[3][r] *= fr;
        }
      }

      // ---- P = exp2(S^T - m), pack to PV A-fragments in-register, PV MFMAs
      float rs = 0.f;
#pragma unroll
      for (int kt = 0; kt < 2; ++kt) {
#pragma unroll
        for (int s = 0; s < 2; ++s) {
          float e0 = fexp2(st[kt][8 * s + 0] - m), e1 = fexp2(st[kt][8 * s + 1] - m);
          float e2 = fexp2(st[kt][8 * s + 2] - m), e3 = fexp2(st[kt][8 * s + 3] - m);
          float e4 = fexp2(st[kt][8 * s + 4] - m), e5 = fexp2(st[kt][8 * s + 5] - m);
          float e6 = fexp2(st[kt][8 * s + 6] - m), e7 = fexp2(st[kt][8 * s + 7] - m);
          rs += ((e0 + e1) + (e2 + e3)) + ((e4 + e5) + (e6 + e7));
          const unsigned wL0 = cvtpk(e0, e1), wL1 = cvtpk(e2, e3);
          const unsigned wH0 = cvtpk(e4, e5), wH1 = cvtpk(e6, e7);
          const unsigned s0 = hi ? wL0 : wH0, s1 = hi ? wL1 : wH1;
          const unsigned r0 = __shfl_xor(s0, 32), r1 = __shfl_xor(s1, 32);
          u32x4 fw;
          fw.x = hi ? r0 : wL0; fw.y = hi ? r1 : wL1;
          fw.z = hi ? wH0 : r0; fw.w = hi ? wH1 : r1;
          const bf16x8 pa = __builtin_bit_cast(bf16x8, fw);
          const int ch = (((kt * 2 + s) << 1) | hi) ^ (l5 & 7);
          __builtin_amdgcn_s_setprio(1);
#pragma unroll
          for (int ds = 0; ds < 4; ++ds) {
            const int vrow = ds * 32 + l5;
            bf16x8 vb = *(const bf16x8*)&Vs[vrow * 64 + (ch << 3)];
            o[ds] = __builtin_amdgcn_mfma_f32_32x32x16_bf16(pa, vb, o[ds], 0, 0, 0);
          }
          __builtin_amdgcn_s_setprio(0);
        }
      }
      rs += __shfl_xor(rs, 32);
      l += rs;
    }
  }

  // ---- epilogue: O /= l, write y[b, q, h*128 + d]
  const float linv = 1.0f / l;
#pragma unroll
  for (int r = 0; r < 16; ++r) {
    const int crow = (r & 3) + ((r >> 2) << 3) + (hi << 2);
    const float lf = __shfl(linv, crow);
    const int qg = q0w + crow;
    const size_t rowoff = (((size_t)(b << 11) + qg) << 11) + (h << 7) + l5;
#pragma unroll
    for (int ds = 0; ds < 4; ++ds)
      y[rowoff + ds * 32] = f2bf(o[ds][r] * lf);
  }
}

// ---------------- launch ----------------
extern "C" void kernel_launch(void* const* d_in, const int* in_sizes, int n_in,
                              void* d_out, int out_size, void* d_ws, size_t ws_size,
                              hipStream_t stream) {
  (void)in_sizes; (void)n_in; (void)out_size; (void)ws_size;
  const float* x    = (const float*)d_in[0];
  const float* wq_w = (const float*)d_in[1];
  const float* wq_b = (const float*)d_in[2];
  const float* wk_w = (const float*)d_in[3];
  const float* wk_b = (const float*)d_in[4];
  const float* wv_w = (const float*)d_in[5];
  const float* wv_b = (const float*)d_in[6];
  const float* cp_w = (const float*)d_in[7];
  const float* cp_b = (const float*)d_in[8];

  char* ws = (char*)d_ws;
  u16* xb  = (u16*)ws;  ws += (size_t)M_ * C_ * 2;        // x bf16; later reused as y
  u16* wqr = (u16*)ws;  ws += (size_t)C_ * C_ * 2;        // rotated wq (rows 0..2047 of Wcat)
  u16* wkr = (u16*)ws;  ws += (size_t)512 * C_ * 2;       // rotated wk (rows 2048..2559)
  u16* wvb = (u16*)ws;  ws += (size_t)512 * C_ * 2;       // wv        (rows 2560..3071)
  u16* cpb = (u16*)ws;  ws += (size_t)C_ * C_ * 2;
  u16* qb  = (u16*)ws;  ws += (size_t)M_ * C_ * 2;
  u16* kb  = (u16*)ws;  ws += (size_t)M_ * 512 * 2;
  u16* vtb = (u16*)ws;  ws += (size_t)M_ * 512 * 2;
  float* bqkv = (float*)ws; ws += 3072 * 4;               // concat bias (fp32)
  u16* yb = xb;

  cvt_bf16<<<8192, 256, 0, stream>>>((const float4*)x,    (ushort4*)xb,  2097152);
  cvt_bf16<<<1024, 256, 0, stream>>>((const float4*)wv_w, (ushort4*)wvb, 262144);
  cvt_bf16<<<4096, 256, 0, stream>>>((const float4*)cp_w, (ushort4*)cpb, 1048576);
  rope_fold_w<<<2048, 256, 0, stream>>>(wq_w, wqr, 1024);
  rope_fold_w<<<512,  256, 0, stream>>>(wk_w, wkr, 256);
  rope_fold_b<<<4, 256, 0, stream>>>(wq_b, bqkv, 1024);
  rope_fold_b<<<1, 256, 0, stream>>>(wk_b, bqkv + 2048, 256);
  copy_f32<<<2, 256, 0, stream>>>(wv_b, bqkv + 2560, 512);

  // Q pre-scaled by log2e / sqrt(HD) so attention softmax runs in exp2 domain
  const float qscale = 0.08838834764831843f * 1.4426950408889634f;
  gemm_qkv<<<dim3(24, 32), 256, 0, stream>>>(xb, wqr, bqkv, qb, kb, vtb, qscale);

  attn2<<<dim3(16, 16, 2), 256, 0, stream>>>(qb, kb, vtb, yb);

  gemm_proj<<<dim3(16, 32), 256, 0, stream>>>(yb, cpb, cp_b, (float*)d_out, 2048);
}

// Round 4
// 211.268 us; speedup vs baseline: 1.7828x; 1.1211x over previous
//
#include <hip/hip_runtime.h>

typedef unsigned short u16;
typedef __bf16 bf16x8 __attribute__((ext_vector_type(8)));
typedef float f32x4 __attribute__((ext_vector_type(4)));
typedef float f32x16 __attribute__((ext_vector_type(16)));
typedef unsigned u32x4 __attribute__((ext_vector_type(4)));

#define T_   2048
#define C_   2048
#define HD_  128
#define NH_  16
#define NKV_ 4
#define M_   4096   // B*T

typedef __attribute__((address_space(1))) const void* as1_cvp;
typedef __attribute__((address_space(3))) void* as3_vp;

__device__ __forceinline__ void gload16(const void* g, void* l) {
  __builtin_amdgcn_global_load_lds((as1_cvp)g, (as3_vp)l, 16, 0, 0);
}

__device__ __forceinline__ u16 f2bf(float f) {
  unsigned u = __builtin_bit_cast(unsigned, f);
  return (u16)((u + 0x7fffu + ((u >> 16) & 1u)) >> 16);
}

__device__ __forceinline__ float fexp2(float x) {
  float r;
  asm("v_exp_f32 %0, %1" : "=v"(r) : "v"(x));
  return r;
}

__device__ __forceinline__ unsigned cvtpk(float a, float b) {
  unsigned d;
  asm("v_cvt_pk_bf16_f32 %0, %1, %2" : "=v"(d) : "v"(a), "v"(b));
  return d;
}

// ---------------- fp32 -> bf16 plain convert ----------------
__global__ void cvt_bf16(const float4* __restrict__ in, ushort4* __restrict__ out, int n4) {
  int i = blockIdx.x * blockDim.x + threadIdx.x;
  if (i >= n4) return;
  float4 v = in[i];
  ushort4 r;
  r.x = f2bf(v.x); r.y = f2bf(v.y); r.z = f2bf(v.z); r.w = f2bf(v.w);
  out[i] = r;
}

__global__ void copy_f32(const float* __restrict__ in, float* __restrict__ out, int n) {
  int i = blockIdx.x * blockDim.x + threadIdx.x;
  if (i < n) out[i] = in[i];
}

// ---------------- RoPE folded into weight rows (angle indexed by HEAD, per reference quirk) ----
__global__ void rope_fold_w(const float* __restrict__ W, u16* __restrict__ out, int npair) {
  int idx = blockIdx.x * blockDim.x + threadIdx.x;
  int p  = idx >> 9;
  int c4 = (idx & 511) << 2;
  if (p >= npair) return;
  int h  = p >> 6;
  int ii = p & 63;
  float theta = __expf(-(float)ii * (9.210340371976184f / 64.0f));
  float s, c;
  __sincosf((float)h * theta, &s, &c);
  size_t r0 = (size_t)(2 * p) * 2048 + c4;
  size_t r1 = r0 + 2048;
  float4 a = *(const float4*)(W + r0);
  float4 b = *(const float4*)(W + r1);
  ushort4 o0, o1;
  o0.x = f2bf(a.x * c - b.x * s); o0.y = f2bf(a.y * c - b.y * s);
  o0.z = f2bf(a.z * c - b.z * s); o0.w = f2bf(a.w * c - b.w * s);
  o1.x = f2bf(b.x * c + a.x * s); o1.y = f2bf(b.y * c + a.y * s);
  o1.z = f2bf(b.z * c + a.z * s); o1.w = f2bf(b.w * c + a.w * s);
  *(ushort4*)(out + r0) = o0;
  *(ushort4*)(out + r1) = o1;
}

__global__ void rope_fold_b(const float* __restrict__ bin, float* __restrict__ bout, int npair) {
  int p = blockIdx.x * blockDim.x + threadIdx.x;
  if (p >= npair) return;
  int h = p >> 6, ii = p & 63;
  float theta = __expf(-(float)ii * (9.210340371976184f / 64.0f));
  float s, c;
  __sincosf((float)h * theta, &s, &c);
  float a = bin[2 * p], b = bin[2 * p + 1];
  bout[2 * p]     = a * c - b * s;
  bout[2 * p + 1] = b * c + a * s;
}

// ---------------- pipelined GEMM: C[M,N] = A[M,2048] @ W[N,2048]^T + bias ----------------
// depth-2 staging (3 LDS slots, counted vmcnt(4) across raw s_barrier), XCD N-strip
// scheduling (each XCD owns NPX N-panels, M-major), chunk-XOR LDS swizzle (2-way free).
// MODE 0: fused QKV epilogue (q scaled / k / v-transposed); MODE 1: fp32 [M,2048] out.
template<int MODE, int NPX>
__global__ __launch_bounds__(256)
void gemm_t(const u16* __restrict__ A, const u16* __restrict__ W,
            const float* __restrict__ bias, void* __restrict__ op0,
            void* __restrict__ op1, void* __restrict__ op2, const float qscale) {
  __shared__ __align__(16) u16 sm[3 * 8192];   // slot s: A[128][32] @ s*8192, B @ +4096
  const int tid  = threadIdx.x;
  const int lane = tid & 63;
  const int wr = (tid >> 6) >> 1, wc = (tid >> 6) & 1;
  const int bid = blockIdx.x;
  const int xcd = bid & 7;
  const int idx = bid >> 3;
  const int mN  = idx / NPX;
  const int nl  = idx - mN * NPX;
  const int m0  = mN << 7;
  const int n0  = (xcd * NPX + nl) << 7;
  const int K = C_;

  const int srow = tid >> 2;
  const int sch  = (tid & 3) ^ ((srow >> 1) & 3);     // pre-swizzled source chunk
  const u16* gA = A + (size_t)(m0 + srow) * K + sch * 8;
  const u16* gW = W + (size_t)(n0 + srow) * K + sch * 8;
  const int ldst = srow * 32 + (tid & 3) * 8;         // linear LDS dest

  const int fr = lane & 15;
  const int g  = lane >> 4;                           // k-chunk 0..3

  f32x4 acc[4][4] = {};

#define STAGE(s, k0)                                          \
  {                                                           \
    u16* base_ = sm + (s) * 8192;                             \
    gload16(gA + (k0),            base_ + ldst);              \
    gload16(gA + (k0) + 64 * K,   base_ + 64 * 32 + ldst);    \
    gload16(gW + (k0),            base_ + 4096 + ldst);       \
    gload16(gW + (k0) + 64 * K,   base_ + 4096 + 64 * 32 + ldst); \
  }

  STAGE(0, 0)
  STAGE(1, 32)
  asm volatile("s_waitcnt vmcnt(4)" ::: "memory");
  __builtin_amdgcn_s_barrier();

  int slot = 0;
  for (int kt = 0; kt < 64; ++kt) {
    int s2 = slot + 2; if (s2 >= 3) s2 -= 3;
    if (kt < 62) STAGE(s2, (kt + 2) * 32)

    const u16* bufA = sm + slot * 8192;
    const u16* bufB = bufA + 4096;
    bf16x8 af[4], bq[4];
#pragma unroll
    for (int mi = 0; mi < 4; ++mi) {
      const int row = wr * 64 + mi * 16 + fr;
      af[mi] = *(const bf16x8*)&bufA[row * 32 + ((g ^ ((row >> 1) & 3)) << 3)];
    }
#pragma unroll
    for (int ni = 0; ni < 4; ++ni) {
      const int row = wc * 64 + ni * 16 + fr;
      bq[ni] = *(const bf16x8*)&bufB[row * 32 + ((g ^ ((row >> 1) & 3)) << 3)];
    }
#pragma unroll
    for (int mi = 0; mi < 4; ++mi)
#pragma unroll
      for (int ni = 0; ni < 4; ++ni)
        acc[mi][ni] = __builtin_amdgcn_mfma_f32_16x16x32_bf16(af[mi], bq[ni], acc[mi][ni], 0, 0, 0);

    __builtin_amdgcn_sched_barrier(0);
    if (kt < 62) asm volatile("s_waitcnt vmcnt(4) lgkmcnt(0)" ::: "memory");
    else         asm volatile("s_waitcnt vmcnt(0) lgkmcnt(0)" ::: "memory");
    __builtin_amdgcn_s_barrier();
    __builtin_amdgcn_sched_barrier(0);
    slot = (slot == 2) ? 0 : slot + 1;
  }
#undef STAGE

  const int rbase = m0 + wr * 64 + ((lane >> 4) << 2);
#pragma unroll
  for (int ni = 0; ni < 4; ++ni) {
    const int cg = n0 + wc * 64 + ni * 16 + fr;
    const float bb = bias[cg];
#pragma unroll
    for (int mi = 0; mi < 4; ++mi) {
      const int rg0 = rbase + mi * 16;
#pragma unroll
      for (int r = 0; r < 4; ++r) {
        float v = acc[mi][ni][r] + bb;
        const int rg = rg0 + r;
        if (MODE == 1) {
          ((float*)op0)[(size_t)rg * C_ + cg] = v;
        } else {
          const int b = rg >> 11, t = rg & (T_ - 1);
          if (cg < 2048) {
            const int h = cg >> 7, d = cg & 127;
            ((u16*)op0)[((((size_t)b * NH_ + h) * T_ + t) << 7) + d] = f2bf(v * qscale);
          } else if (cg < 2560) {
            const int c2 = cg - 2048, h = c2 >> 7, d = c2 & 127;
            ((u16*)op1)[((((size_t)b * NKV_ + h) * T_ + t) << 7) + d] = f2bf(v);
          } else {
            const int c2 = cg - 2560, h = c2 >> 7, d = c2 & 127;
            ((u16*)op2)[(((size_t)b * NKV_ + h) * HD_ + d) * T_ + t] = f2bf(v);
          }
        }
      }
    }
  }
}

// ---------------- causal GQA flash attention (4 warps x 32 q-rows, 32x32x16 MFMA) ------------
__device__ __forceinline__ void stage_kv(u16* dst, const u16* __restrict__ kg,
                                         const u16* __restrict__ vg, int lane, int w) {
#pragma unroll
  for (int r = 0; r < 4; ++r) {           // K: 64 rows x 16 chunks
    const int row = r * 16 + w * 4 + (lane >> 4);
    const int cg  = (lane & 15) ^ (row & 7);
    gload16(kg + (size_t)row * 128 + cg * 8, dst + row * 128 + (lane & 15) * 8);
  }
#pragma unroll
  for (int r = 0; r < 4; ++r) {           // Vt: 128 rows x 8 chunks
    const int row = r * 32 + w * 8 + (lane >> 3);
    const int cg  = (lane & 7) ^ (row & 7);
    gload16(vg + (size_t)row * T_ + cg * 8, dst + 8192 + row * 64 + (lane & 7) * 8);
  }
}

__global__ __launch_bounds__(256, 2)
void attn2(const u16* __restrict__ q, const u16* __restrict__ k,
           const u16* __restrict__ vt, u16* __restrict__ y) {
  __shared__ __align__(16) u16 sm[32768];
  const int tid  = threadIdx.x;
  const int lane = tid & 63;
  const int w    = tid >> 6;
  const int hi   = lane >> 5;
  const int l5   = lane & 31;
  const int h = blockIdx.y;
  const int b = blockIdx.z;
  // complementary pairing: co-resident (x,y,0)/(x,y,1) get qt summing to 15 -> uniform CU load
  const int qt = b ? (int)blockIdx.x : (15 - (int)blockIdx.x);
  const int q0  = qt << 7;
  const int q0w = q0 + w * 32;
  const int nkv = 2 * qt + 2;
  const size_t qbase = (((size_t)b * NH_ + h) * T_ + q0) * HD_;
  const size_t kbase = ((size_t)b * NKV_ + (h >> 2)) * (size_t)T_ * HD_;
  const size_t vbase = ((size_t)b * NKV_ + (h >> 2)) * (size_t)HD_ * T_;

  // ---- stage Q [128][128] (swizzled) into sm[0..16384)
#pragma unroll
  for (int r = 0; r < 8; ++r) {
    const int row = r * 16 + w * 4 + (lane >> 4);
    const int cg  = (lane & 15) ^ (row & 7);
    gload16(q + qbase + (size_t)row * 128 + cg * 8, sm + row * 128 + (lane & 15) * 8);
  }
  __syncthreads();
  bf16x8 qf[8];
  {
    const int row = w * 32 + l5;
#pragma unroll
    for (int kd = 0; kd < 8; ++kd)
      qf[kd] = *(const bf16x8*)&sm[row * 128 + ((((kd << 1) | hi) ^ (row & 7)) << 3)];
  }
  __syncthreads();
  stage_kv(sm, k + kbase, vt + vbase, lane, w);

  f32x16 o[4] = {};
  float m = -1e30f, l = 0.f;

  for (int kv = 0; kv < nkv; ++kv) {
    __syncthreads();               // staging of current buf complete (vmcnt(0)+barrier)
    const int buf = kv & 1;
    if (kv + 1 < nkv)
      stage_kv(sm + ((buf ^ 1) << 14),
               k + kbase + ((size_t)(kv + 1) << 6) * 128,
               vt + vbase + ((kv + 1) << 6), lane, w);

    if ((kv << 6) <= q0w + 31) {
      const u16* Ks = sm + (buf << 14);
      const u16* Vs = Ks + 8192;

      // ---- S^T = K @ Q^T : lane holds S^T[k=crow(r,hi)][q=l5]
      f32x16 st[2] = {};
      __builtin_amdgcn_s_setprio(1);
#pragma unroll
      for (int kt = 0; kt < 2; ++kt) {
        const int krow = kt * 32 + l5;
#pragma unroll
        for (int kd = 0; kd < 8; ++kd) {
          bf16x8 ka = *(const bf16x8*)&Ks[krow * 128 + ((((kd << 1) | hi) ^ (l5 & 7)) << 3)];
          st[kt] = __builtin_amdgcn_mfma_f32_32x32x16_bf16(ka, qf[kd], st[kt], 0, 0, 0);
        }
      }
      __builtin_amdgcn_s_setprio(0);

      // ---- causal mask (diagonal tiles only)
      if ((kv << 6) + 63 > q0w) {
        const int qg = q0w + l5;
#pragma unroll
        for (int kt = 0; kt < 2; ++kt)
#pragma unroll
          for (int r = 0; r < 16; ++r) {
            const int kg = (kv << 6) + kt * 32 + (r & 3) + ((r >> 2) << 3) + (hi << 2);
            if (kg > qg) st[kt][r] = -3.0e38f;
          }
      }

      // ---- online softmax (log2 domain; scale folded into Q)
      float pmax = -3.0e38f;
#pragma unroll
      for (int kt = 0; kt < 2; ++kt)
#pragma unroll
        for (int r = 0; r < 16; ++r) pmax = fmaxf(pmax, st[kt][r]);
      pmax = fmaxf(pmax, __shfl_xor(pmax, 32));
      if (!__all(pmax - m <= 8.0f)) {        // defer-max (T13)
        const float mn = fmaxf(m, pmax);
        const float f = fexp2(m - mn);
        m = mn;
        l *= f;
#pragma unroll
        for (int r = 0; r < 16; ++r) {
          const float fr = __shfl(f, (r & 3) + ((r >> 2) << 3) + (hi << 2));
          o[0][r] *= fr; o[1][r] *= fr; o[2][r] *= fr; o[3][r] *= fr;
        }
      }

      // ---- P = exp2(S^T - m), pack to PV A-fragments in-register, PV MFMAs
      float rs = 0.f;
#pragma unroll
      for (int kt = 0; kt < 2; ++kt) {
#pragma unroll
        for (int s = 0; s < 2; ++s) {
          float e0 = fexp2(st[kt][8 * s + 0] - m), e1 = fexp2(st[kt][8 * s + 1] - m);
          float e2 = fexp2(st[kt][8 * s + 2] - m), e3 = fexp2(st[kt][8 * s + 3] - m);
          float e4 = fexp2(st[kt][8 * s + 4] - m), e5 = fexp2(st[kt][8 * s + 5] - m);
          float e6 = fexp2(st[kt][8 * s + 6] - m), e7 = fexp2(st[kt][8 * s + 7] - m);
          rs += ((e0 + e1) + (e2 + e3)) + ((e4 + e5) + (e6 + e7));
          const unsigned wL0 = cvtpk(e0, e1), wL1 = cvtpk(e2, e3);
          const unsigned wH0 = cvtpk(e4, e5), wH1 = cvtpk(e6, e7);
          const unsigned s0 = hi ? wL0 : wH0, s1 = hi ? wL1 : wH1;
          const unsigned r0 = __shfl_xor(s0, 32), r1 = __shfl_xor(s1, 32);
          u32x4 fw;
          fw.x = hi ? r0 : wL0; fw.y = hi ? r1 : wL1;
          fw.z = hi ? wH0 : r0; fw.w = hi ? wH1 : r1;
          const bf16x8 pa = __builtin_bit_cast(bf16x8, fw);
          const int ch = (((kt * 2 + s) << 1) | hi) ^ (l5 & 7);
          __builtin_amdgcn_s_setprio(1);
#pragma unroll
          for (int ds = 0; ds < 4; ++ds) {
            const int vrow = ds * 32 + l5;
            bf16x8 vb = *(const bf16x8*)&Vs[vrow * 64 + (ch << 3)];
            o[ds] = __builtin_amdgcn_mfma_f32_32x32x16_bf16(pa, vb, o[ds], 0, 0, 0);
          }
          __builtin_amdgcn_s_setprio(0);
        }
      }
      rs += __shfl_xor(rs, 32);
      l += rs;
    }
  }

  // ---- epilogue: O /= l, write y[b, q, h*128 + d]
  const float linv = 1.0f / l;
#pragma unroll
  for (int r = 0; r < 16; ++r) {
    const int crow = (r & 3) + ((r >> 2) << 3) + (hi << 2);
    const float lf = __shfl(linv, crow);
    const int qg = q0w + crow;
    const size_t rowoff = (((size_t)(b << 11) + qg) << 11) + (h << 7) + l5;
#pragma unroll
    for (int ds = 0; ds < 4; ++ds)
      y[rowoff + ds * 32] = f2bf(o[ds][r] * lf);
  }
}

// ---------------- launch ----------------
extern "C" void kernel_launch(void* const* d_in, const int* in_sizes, int n_in,
                              void* d_out, int out_size, void* d_ws, size_t ws_size,
                              hipStream_t stream) {
  (void)in_sizes; (void)n_in; (void)out_size; (void)ws_size;
  const float* x    = (const float*)d_in[0];
  const float* wq_w = (const float*)d_in[1];
  const float* wq_b = (const float*)d_in[2];
  const float* wk_w = (const float*)d_in[3];
  const float* wk_b = (const float*)d_in[4];
  const float* wv_w = (const float*)d_in[5];
  const float* wv_b = (const float*)d_in[6];
  const float* cp_w = (const float*)d_in[7];
  const float* cp_b = (const float*)d_in[8];

  char* ws = (char*)d_ws;
  u16* xb  = (u16*)ws;  ws += (size_t)M_ * C_ * 2;        // x bf16; later reused as y
  u16* wqr = (u16*)ws;  ws += (size_t)C_ * C_ * 2;        // rotated wq (rows 0..2047 of Wcat)
  u16* wkr = (u16*)ws;  ws += (size_t)512 * C_ * 2;       // rotated wk (rows 2048..2559)
  u16* wvb = (u16*)ws;  ws += (size_t)512 * C_ * 2;       // wv        (rows 2560..3071)
  u16* cpb = (u16*)ws;  ws += (size_t)C_ * C_ * 2;
  u16* qb  = (u16*)ws;  ws += (size_t)M_ * C_ * 2;
  u16* kb  = (u16*)ws;  ws += (size_t)M_ * 512 * 2;
  u16* vtb = (u16*)ws;  ws += (size_t)M_ * 512 * 2;
  float* bqkv = (float*)ws; ws += 3072 * 4;               // concat bias (fp32)
  u16* yb = xb;

  cvt_bf16<<<8192, 256, 0, stream>>>((const float4*)x,    (ushort4*)xb,  2097152);
  cvt_bf16<<<1024, 256, 0, stream>>>((const float4*)wv_w, (ushort4*)wvb, 262144);
  cvt_bf16<<<4096, 256, 0, stream>>>((const float4*)cp_w, (ushort4*)cpb, 1048576);
  rope_fold_w<<<2048, 256, 0, stream>>>(wq_w, wqr, 1024);
  rope_fold_w<<<512,  256, 0, stream>>>(wk_w, wkr, 256);
  rope_fold_b<<<4, 256, 0, stream>>>(wq_b, bqkv, 1024);
  rope_fold_b<<<1, 256, 0, stream>>>(wk_b, bqkv + 2048, 256);
  copy_f32<<<2, 256, 0, stream>>>(wv_b, bqkv + 2560, 512);

  // Q pre-scaled by log2e / sqrt(HD) so attention softmax runs in exp2 domain
  const float qscale = 0.08838834764831843f * 1.4426950408889634f;
  gemm_t<0, 3><<<768, 256, 0, stream>>>(xb, wqr, bqkv, qb, kb, vtb, qscale);

  attn2<<<dim3(16, 16, 2), 256, 0, stream>>>(qb, kb, vtb, yb);

  gemm_t<1, 2><<<512, 256, 0, stream>>>(yb, cpb, cp_b, (float*)d_out, nullptr, nullptr, 1.0f);
}

// Round 5
// 192.977 us; speedup vs baseline: 1.9518x; 1.0948x over previous
//
#include <hip/hip_runtime.h>

typedef unsigned short u16;
typedef __bf16 bf16x8 __attribute__((ext_vector_type(8)));
typedef float f32x4 __attribute__((ext_vector_type(4)));
typedef float f32x16 __attribute__((ext_vector_type(16)));
typedef unsigned u32x4 __attribute__((ext_vector_type(4)));

#define T_   2048
#define C_   2048
#define HD_  128
#define NH_  16
#define NKV_ 4
#define M_   4096   // B*T

typedef __attribute__((address_space(1))) const void* as1_cvp;
typedef __attribute__((address_space(3))) void* as3_vp;

__device__ __forceinline__ void gload16(const void* g, void* l) {
  __builtin_amdgcn_global_load_lds((as1_cvp)g, (as3_vp)l, 16, 0, 0);
}

__device__ __forceinline__ u16 f2bf(float f) {
  unsigned u = __builtin_bit_cast(unsigned, f);
  return (u16)((u + 0x7fffu + ((u >> 16) & 1u)) >> 16);
}

__device__ __forceinline__ float fexp2(float x) {
  float r;
  asm("v_exp_f32 %0, %1" : "=v"(r) : "v"(x));
  return r;
}

__device__ __forceinline__ unsigned cvtpk(float a, float b) {
  unsigned d;
  asm("v_cvt_pk_bf16_f32 %0, %1, %2" : "=v"(d) : "v"(a), "v"(b));
  return d;
}

// ---------------- fp32 -> bf16 plain convert ----------------
__global__ void cvt_bf16(const float4* __restrict__ in, ushort4* __restrict__ out, int n4) {
  int i = blockIdx.x * blockDim.x + threadIdx.x;
  if (i >= n4) return;
  float4 v = in[i];
  ushort4 r;
  r.x = f2bf(v.x); r.y = f2bf(v.y); r.z = f2bf(v.z); r.w = f2bf(v.w);
  out[i] = r;
}

__global__ void copy_f32(const float* __restrict__ in, float* __restrict__ out, int n) {
  int i = blockIdx.x * blockDim.x + threadIdx.x;
  if (i < n) out[i] = in[i];
}

// ---------------- RoPE folded into weight rows (angle indexed by HEAD, per reference quirk) ----
__global__ void rope_fold_w(const float* __restrict__ W, u16* __restrict__ out, int npair) {
  int idx = blockIdx.x * blockDim.x + threadIdx.x;
  int p  = idx >> 9;
  int c4 = (idx & 511) << 2;
  if (p >= npair) return;
  int h  = p >> 6;
  int ii = p & 63;
  float theta = __expf(-(float)ii * (9.210340371976184f / 64.0f));
  float s, c;
  __sincosf((float)h * theta, &s, &c);
  size_t r0 = (size_t)(2 * p) * 2048 + c4;
  size_t r1 = r0 + 2048;
  float4 a = *(const float4*)(W + r0);
  float4 b = *(const float4*)(W + r1);
  ushort4 o0, o1;
  o0.x = f2bf(a.x * c - b.x * s); o0.y = f2bf(a.y * c - b.y * s);
  o0.z = f2bf(a.z * c - b.z * s); o0.w = f2bf(a.w * c - b.w * s);
  o1.x = f2bf(b.x * c + a.x * s); o1.y = f2bf(b.y * c + a.y * s);
  o1.z = f2bf(b.z * c + a.z * s); o1.w = f2bf(b.w * c + a.w * s);
  *(ushort4*)(out + r0) = o0;
  *(ushort4*)(out + r1) = o1;
}

__global__ void rope_fold_b(const float* __restrict__ bin, float* __restrict__ bout, int npair) {
  int p = blockIdx.x * blockDim.x + threadIdx.x;
  if (p >= npair) return;
  int h = p >> 6, ii = p & 63;
  float theta = __expf(-(float)ii * (9.210340371976184f / 64.0f));
  float s, c;
  __sincosf((float)h * theta, &s, &c);
  float a = bin[2 * p], b = bin[2 * p + 1];
  bout[2 * p]     = a * c - b * s;
  bout[2 * p + 1] = b * c + a * s;
}

// ---------------- 8-wave phase-split GEMM: C[M,N] = A[M,2048] @ W[N,2048]^T + bias ----------
// BM=256, BK=64, 8 waves (2 M x 4 N), 4 phases per K-tile (mh x kc quadrants), raw
// s_barrier between phases (staging loads stay in flight across them), __syncthreads at
// K-tile end (its vmcnt(0) is exactly the counted wait: only next-tile stages in flight).
// Chunk-XOR LDS swizzle (phys_chunk = chunk ^ (row&7)) via pre-swizzled global source.
// MODE 0: fused QKV epilogue (BN=192); MODE 1: fp32 [M,2048] out (BN=128).
template<int BN, int MODE>
__global__ __launch_bounds__(512)
void gemm8(const u16* __restrict__ A, const u16* __restrict__ W,
           const float* __restrict__ bias, void* __restrict__ op0,
           void* __restrict__ op1, void* __restrict__ op2, const float qscale) {
  constexpr int NREP = BN / 64;            // n-frags per wave (3 or 2)
  constexpr int ASZ  = 256 * 64;           // A-tile u16
  constexpr int BSZ  = BN * 64;            // B-tile u16
  constexpr int BUF  = ASZ + BSZ;
  constexpr int NB   = BSZ / 4096;         // B gloads per thread (3 or 2)
  __shared__ __align__(16) u16 sm[2 * BUF];
  const int tid  = threadIdx.x;
  const int lane = tid & 63;
  const int wid  = tid >> 6;
  const int wr = wid >> 2, wc = wid & 3;
  const int m0 = blockIdx.y << 8;
  const int n0 = blockIdx.x * BN;
  const int K  = C_;
  const int fr = lane & 15, g = lane >> 4;

  // staging address precompute (pre-swizzled source chunk, linear LDS dest)
  const u16* srcA[4]; int dstA[4];
#pragma unroll
  for (int i = 0; i < 4; ++i) {
    const int idx = i * 512 + tid;
    const int row = idx >> 3, sch = (idx & 7) ^ (row & 7);
    srcA[i] = A + (size_t)(m0 + row) * K + sch * 8;
    dstA[i] = idx * 8;
  }
  const u16* srcB[NB]; int dstB[NB];
#pragma unroll
  for (int i = 0; i < NB; ++i) {
    const int idx = i * 512 + tid;
    const int row = idx >> 3, sch = (idx & 7) ^ (row & 7);
    srcB[i] = W + (size_t)(n0 + row) * K + sch * 8;
    dstB[i] = ASZ + idx * 8;
  }
  // ds_read swizzled k-chunk offsets (row&7 == fr&7 for all frag rows)
  const int swz0 = ((g     ^ (fr & 7)) << 3);
  const int swz1 = (((4+g) ^ (fr & 7)) << 3);

  f32x4 acc[8][NREP] = {};

  // prologue: stage tile 0 into buf 0
#pragma unroll
  for (int i = 0; i < 4; ++i) gload16(srcA[i], sm + dstA[i]);
#pragma unroll
  for (int i = 0; i < NB; ++i) gload16(srcB[i], sm + dstB[i]);
  __syncthreads();

#define LDA(MH, SWZ) {                                                   \
  _Pragma("unroll")                                                      \
  for (int mi = 0; mi < 4; ++mi) {                                       \
    const int row = wr * 128 + (MH) * 64 + mi * 16 + fr;                 \
    af[mi] = *(const bf16x8*)&sm[base + row * 64 + (SWZ)];               \
  } }
#define LDB(BF, SWZ) {                                                   \
  _Pragma("unroll")                                                      \
  for (int ni = 0; ni < NREP; ++ni) {                                    \
    const int row = wc * (BN / 4) + ni * 16 + fr;                        \
    BF[ni] = *(const bf16x8*)&sm[base + ASZ + row * 64 + (SWZ)];         \
  } }
#define MM(MH, BF) {                                                     \
  __builtin_amdgcn_s_setprio(1);                                         \
  _Pragma("unroll")                                                      \
  for (int mi = 0; mi < 4; ++mi)                                         \
    _Pragma("unroll")                                                    \
    for (int ni = 0; ni < NREP; ++ni)                                    \
      acc[(MH) * 4 + mi][ni] = __builtin_amdgcn_mfma_f32_16x16x32_bf16(  \
          af[mi], BF[ni], acc[(MH) * 4 + mi][ni], 0, 0, 0);              \
  __builtin_amdgcn_s_setprio(0); }

  for (int t = 0; t < 32; ++t) {
    const int base = (t & 1) * BUF;
    const int pbuf = ((t & 1) ^ 1) * BUF;
    bf16x8 af[4], bfa[NREP], bfb[NREP];
    // ---- phase 0 (mh0, kc0): issue all A stages for tile t+1
    if (t < 31) {
      const int ko = (t + 1) * 64;
#pragma unroll
      for (int i = 0; i < 4; ++i) gload16(srcA[i] + ko, sm + pbuf + dstA[i]);
      __builtin_amdgcn_sched_barrier(0);
    }
    LDA(0, swz0) LDB(bfa, swz0) MM(0, bfa)
    __builtin_amdgcn_s_barrier();
    // ---- phase 1 (mh1, kc0): issue all B stages
    if (t < 31) {
      const int ko = (t + 1) * 64;
#pragma unroll
      for (int i = 0; i < NB; ++i) gload16(srcB[i] + ko, sm + pbuf + dstB[i]);
      __builtin_amdgcn_sched_barrier(0);
    }
    LDA(1, swz0) MM(1, bfa)
    __builtin_amdgcn_s_barrier();
    // ---- phase 2 (mh0, kc1)
    LDB(bfb, swz1) LDA(0, swz1) MM(0, bfb)
    __builtin_amdgcn_s_barrier();
    // ---- phase 3 (mh1, kc1); tile-end full sync (drains next-tile stages)
    LDA(1, swz1) MM(1, bfb)
    __syncthreads();
  }
#undef LDA
#undef LDB
#undef MM

  // ---- epilogue
#pragma unroll
  for (int mh = 0; mh < 2; ++mh)
#pragma unroll
    for (int mi = 0; mi < 4; ++mi) {
      const int rg0 = m0 + wr * 128 + mh * 64 + mi * 16 + ((lane >> 4) << 2);
#pragma unroll
      for (int ni = 0; ni < NREP; ++ni) {
        const int cg = n0 + wc * (BN / 4) + ni * 16 + fr;
        const float bb = bias[cg];
#pragma unroll
        for (int r = 0; r < 4; ++r) {
          float v = acc[mh * 4 + mi][ni][r] + bb;
          const int rg = rg0 + r;
          if (MODE == 1) {
            ((float*)op0)[(size_t)rg * C_ + cg] = v;
          } else {
            const int b = rg >> 11, t = rg & (T_ - 1);
            if (cg < 2048) {
              const int h = cg >> 7, d = cg & 127;
              ((u16*)op0)[((((size_t)b * NH_ + h) * T_ + t) << 7) + d] = f2bf(v * qscale);
            } else if (cg < 2560) {
              const int c2 = cg - 2048, h = c2 >> 7, d = c2 & 127;
              ((u16*)op1)[((((size_t)b * NKV_ + h) * T_ + t) << 7) + d] = f2bf(v);
            } else {
              const int c2 = cg - 2560, h = c2 >> 7, d = c2 & 127;
              ((u16*)op2)[(((size_t)b * NKV_ + h) * HD_ + d) * T_ + t] = f2bf(v);
            }
          }
        }
      }
    }
}

// ---------------- causal GQA flash attention (4 warps x 32 q-rows, 32x32x16 MFMA) ------------
__device__ __forceinline__ void stage_kv(u16* dst, const u16* __restrict__ kg,
                                         const u16* __restrict__ vg, int lane, int w) {
#pragma unroll
  for (int r = 0; r < 4; ++r) {           // K: 64 rows x 16 chunks
    const int row = r * 16 + w * 4 + (lane >> 4);
    const int cg  = (lane & 15) ^ (row & 7);
    gload16(kg + (size_t)row * 128 + cg * 8, dst + row * 128 + (lane & 15) * 8);
  }
#pragma unroll
  for (int r = 0; r < 4; ++r) {           // Vt: 128 rows x 8 chunks
    const int row = r * 32 + w * 8 + (lane >> 3);
    const int cg  = (lane & 7) ^ (row & 7);
    gload16(vg + (size_t)row * T_ + cg * 8, dst + 8192 + row * 64 + (lane & 7) * 8);
  }
}

__global__ __launch_bounds__(256, 2)
void attn2(const u16* __restrict__ q, const u16* __restrict__ k,
           const u16* __restrict__ vt, u16* __restrict__ y) {
  __shared__ __align__(16) u16 sm[32768];
  const int tid  = threadIdx.x;
  const int lane = tid & 63;
  const int w    = tid >> 6;
  const int hi   = lane >> 5;
  const int l5   = lane & 31;
  const int h = blockIdx.y;
  const int b = blockIdx.z;
  // complementary pairing: co-resident (x,y,0)/(x,y,1) get qt summing to 15 -> uniform CU load
  const int qt = b ? (int)blockIdx.x : (15 - (int)blockIdx.x);
  const int q0  = qt << 7;
  const int q0w = q0 + w * 32;
  const int nkv = 2 * qt + 2;
  const size_t qbase = (((size_t)b * NH_ + h) * T_ + q0) * HD_;
  const size_t kbase = ((size_t)b * NKV_ + (h >> 2)) * (size_t)T_ * HD_;
  const size_t vbase = ((size_t)b * NKV_ + (h >> 2)) * (size_t)HD_ * T_;

  // ---- stage Q [128][128] (swizzled) into sm[0..16384)
#pragma unroll
  for (int r = 0; r < 8; ++r) {
    const int row = r * 16 + w * 4 + (lane >> 4);
    const int cg  = (lane & 15) ^ (row & 7);
    gload16(q + qbase + (size_t)row * 128 + cg * 8, sm + row * 128 + (lane & 15) * 8);
  }
  __syncthreads();
  bf16x8 qf[8];
  {
    const int row = w * 32 + l5;
#pragma unroll
    for (int kd = 0; kd < 8; ++kd)
      qf[kd] = *(const bf16x8*)&sm[row * 128 + ((((kd << 1) | hi) ^ (row & 7)) << 3)];
  }
  __syncthreads();
  stage_kv(sm, k + kbase, vt + vbase, lane, w);

  f32x16 o[4] = {};
  float m = -1e30f, l = 0.f;

  for (int kv = 0; kv < nkv; ++kv) {
    __syncthreads();               // staging of current buf complete (vmcnt(0)+barrier)
    const int buf = kv & 1;
    if (kv + 1 < nkv)
      stage_kv(sm + ((buf ^ 1) << 14),
               k + kbase + ((size_t)(kv + 1) << 6) * 128,
               vt + vbase + ((kv + 1) << 6), lane, w);

    if ((kv << 6) <= q0w + 31) {
      const u16* Ks = sm + (buf << 14);
      const u16* Vs = Ks + 8192;

      // ---- S^T = K @ Q^T : lane holds S^T[k=crow(r,hi)][q=l5]
      f32x16 st[2] = {};
      __builtin_amdgcn_s_setprio(1);
#pragma unroll
      for (int kt = 0; kt < 2; ++kt) {
        const int krow = kt * 32 + l5;
#pragma unroll
        for (int kd = 0; kd < 8; ++kd) {
          bf16x8 ka = *(const bf16x8*)&Ks[krow * 128 + ((((kd << 1) | hi) ^ (l5 & 7)) << 3)];
          st[kt] = __builtin_amdgcn_mfma_f32_32x32x16_bf16(ka, qf[kd], st[kt], 0, 0, 0);
        }
      }
      __builtin_amdgcn_s_setprio(0);

      // ---- causal mask (diagonal tiles only)
      if ((kv << 6) + 63 > q0w) {
        const int qg = q0w + l5;
#pragma unroll
        for (int kt = 0; kt < 2; ++kt)
#pragma unroll
          for (int r = 0; r < 16; ++r) {
            const int kg = (kv << 6) + kt * 32 + (r & 3) + ((r >> 2) << 3) + (hi << 2);
            if (kg > qg) st[kt][r] = -3.0e38f;
          }
      }

      // ---- online softmax (log2 domain; scale folded into Q)
      float pmax = -3.0e38f;
#pragma unroll
      for (int kt = 0; kt < 2; ++kt)
#pragma unroll
        for (int r = 0; r < 16; ++r) pmax = fmaxf(pmax, st[kt][r]);
      pmax = fmaxf(pmax, __shfl_xor(pmax, 32));
      if (!__all(pmax - m <= 8.0f)) {        // defer-max (T13)
        const float mn = fmaxf(m, pmax);
        const float f = fexp2(m - mn);
        m = mn;
        l *= f;
#pragma unroll
        for (int r = 0; r < 16; ++r) {
          const float fr = __shfl(f, (r & 3) + ((r >> 2) << 3) + (hi << 2));
          o[0][r] *= fr; o[1][r] *= fr; o[2][r] *= fr; o[3][r] *= fr;
        }
      }

      // ---- P = exp2(S^T - m), pack to PV A-fragments in-register, PV MFMAs
      float rs = 0.f;
#pragma unroll
      for (int kt = 0; kt < 2; ++kt) {
#pragma unroll
        for (int s = 0; s < 2; ++s) {
          float e0 = fexp2(st[kt][8 * s + 0] - m), e1 = fexp2(st[kt][8 * s + 1] - m);
          float e2 = fexp2(st[kt][8 * s + 2] - m), e3 = fexp2(st[kt][8 * s + 3] - m);
          float e4 = fexp2(st[kt][8 * s + 4] - m), e5 = fexp2(st[kt][8 * s + 5] - m);
          float e6 = fexp2(st[kt][8 * s + 6] - m), e7 = fexp2(st[kt][8 * s + 7] - m);
          rs += ((e0 + e1) + (e2 + e3)) + ((e4 + e5) + (e6 + e7));
          const unsigned wL0 = cvtpk(e0, e1), wL1 = cvtpk(e2, e3);
          const unsigned wH0 = cvtpk(e4, e5), wH1 = cvtpk(e6, e7);
          const unsigned s0 = hi ? wL0 : wH0, s1 = hi ? wL1 : wH1;
          const unsigned r0 = __shfl_xor(s0, 32), r1 = __shfl_xor(s1, 32);
          u32x4 fw;
          fw.x = hi ? r0 : wL0; fw.y = hi ? r1 : wL1;
          fw.z = hi ? wH0 : r0; fw.w = hi ? wH1 : r1;
          const bf16x8 pa = __builtin_bit_cast(bf16x8, fw);
          const int ch = (((kt * 2 + s) << 1) | hi) ^ (l5 & 7);
          __builtin_amdgcn_s_setprio(1);
#pragma unroll
          for (int ds = 0; ds < 4; ++ds) {
            const int vrow = ds * 32 + l5;
            bf16x8 vb = *(const bf16x8*)&Vs[vrow * 64 + (ch << 3)];
            o[ds] = __builtin_amdgcn_mfma_f32_32x32x16_bf16(pa, vb, o[ds], 0, 0, 0);
          }
          __builtin_amdgcn_s_setprio(0);
        }
      }
      rs += __shfl_xor(rs, 32);
      l += rs;
    }
  }

  // ---- epilogue: O /= l, write y[b, q, h*128 + d]
  const float linv = 1.0f / l;
#pragma unroll
  for (int r = 0; r < 16; ++r) {
    const int crow = (r & 3) + ((r >> 2) << 3) + (hi << 2);
    const float lf = __shfl(linv, crow);
    const int qg = q0w + crow;
    const size_t rowoff = (((size_t)(b << 11) + qg) << 11) + (h << 7) + l5;
#pragma unroll
    for (int ds = 0; ds < 4; ++ds)
      y[rowoff + ds * 32] = f2bf(o[ds][r] * lf);
  }
}

// ---------------- launch ----------------
extern "C" void kernel_launch(void* const* d_in, const int* in_sizes, int n_in,
                              void* d_out, int out_size, void* d_ws, size_t ws_size,
                              hipStream_t stream) {
  (void)in_sizes; (void)n_in; (void)out_size; (void)ws_size;
  const float* x    = (const float*)d_in[0];
  const float* wq_w = (const float*)d_in[1];
  const float* wq_b = (const float*)d_in[2];
  const float* wk_w = (const float*)d_in[3];
  const float* wk_b = (const float*)d_in[4];
  const float* wv_w = (const float*)d_in[5];
  const float* wv_b = (const float*)d_in[6];
  const float* cp_w = (const float*)d_in[7];
  const float* cp_b = (const float*)d_in[8];

  char* ws = (char*)d_ws;
  u16* xb  = (u16*)ws;  ws += (size_t)M_ * C_ * 2;        // x bf16; later reused as y
  u16* wqr = (u16*)ws;  ws += (size_t)C_ * C_ * 2;        // rotated wq (rows 0..2047 of Wcat)
  u16* wkr = (u16*)ws;  ws += (size_t)512 * C_ * 2;       // rotated wk (rows 2048..2559)
  u16* wvb = (u16*)ws;  ws += (size_t)512 * C_ * 2;       // wv        (rows 2560..3071)
  u16* cpb = (u16*)ws;  ws += (size_t)C_ * C_ * 2;
  u16* qb  = (u16*)ws;  ws += (size_t)M_ * C_ * 2;
  u16* kb  = (u16*)ws;  ws += (size_t)M_ * 512 * 2;
  u16* vtb = (u16*)ws;  ws += (size_t)M_ * 512 * 2;
  float* bqkv = (float*)ws; ws += 3072 * 4;               // concat bias (fp32)
  u16* yb = xb;

  cvt_bf16<<<8192, 256, 0, stream>>>((const float4*)x,    (ushort4*)xb,  2097152);
  cvt_bf16<<<1024, 256, 0, stream>>>((const float4*)wv_w, (ushort4*)wvb, 262144);
  cvt_bf16<<<4096, 256, 0, stream>>>((const float4*)cp_w, (ushort4*)cpb, 1048576);
  rope_fold_w<<<2048, 256, 0, stream>>>(wq_w, wqr, 1024);
  rope_fold_w<<<512,  256, 0, stream>>>(wk_w, wkr, 256);
  rope_fold_b<<<4, 256, 0, stream>>>(wq_b, bqkv, 1024);
  rope_fold_b<<<1, 256, 0, stream>>>(wk_b, bqkv + 2048, 256);
  copy_f32<<<2, 256, 0, stream>>>(wv_b, bqkv + 2560, 512);

  // Q pre-scaled by log2e / sqrt(HD) so attention softmax runs in exp2 domain
  const float qscale = 0.08838834764831843f * 1.4426950408889634f;
  gemm8<192, 0><<<dim3(16, 16), 512, 0, stream>>>(xb, wqr, bqkv, qb, kb, vtb, qscale);

  attn2<<<dim3(16, 16, 2), 256, 0, stream>>>(qb, kb, vtb, yb);

  gemm8<128, 1><<<dim3(16, 16), 512, 0, stream>>>(yb, cpb, cp_b, (float*)d_out,
                                                  nullptr, nullptr, 1.0f);
}

// Round 6
// 191.959 us; speedup vs baseline: 1.9622x; 1.0053x over previous
//
#include <hip/hip_runtime.h>

typedef unsigned short u16;
typedef __bf16 bf16x8 __attribute__((ext_vector_type(8)));
typedef float f32x4 __attribute__((ext_vector_type(4)));
typedef float f32x16 __attribute__((ext_vector_type(16)));
typedef unsigned u32x4 __attribute__((ext_vector_type(4)));

#define T_   2048
#define C_   2048
#define HD_  128
#define NH_  16
#define NKV_ 4
#define M_   4096   // B*T

typedef __attribute__((address_space(1))) const void* as1_cvp;
typedef __attribute__((address_space(3))) void* as3_vp;

__device__ __forceinline__ void gload16(const void* g, void* l) {
  __builtin_amdgcn_global_load_lds((as1_cvp)g, (as3_vp)l, 16, 0, 0);
}

__device__ __forceinline__ u16 f2bf(float f) {
  unsigned u = __builtin_bit_cast(unsigned, f);
  return (u16)((u + 0x7fffu + ((u >> 16) & 1u)) >> 16);
}

__device__ __forceinline__ float fexp2(float x) {
  float r;
  asm("v_exp_f32 %0, %1" : "=v"(r) : "v"(x));
  return r;
}

__device__ __forceinline__ unsigned cvtpk(float a, float b) {
  unsigned d;
  asm("v_cvt_pk_bf16_f32 %0, %1, %2" : "=v"(d) : "v"(a), "v"(b));
  return d;
}

// ---------------- fp32 -> bf16 plain convert ----------------
__global__ void cvt_bf16(const float4* __restrict__ in, ushort4* __restrict__ out, int n4) {
  int i = blockIdx.x * blockDim.x + threadIdx.x;
  if (i >= n4) return;
  float4 v = in[i];
  ushort4 r;
  r.x = f2bf(v.x); r.y = f2bf(v.y); r.z = f2bf(v.z); r.w = f2bf(v.w);
  out[i] = r;
}

__global__ void copy_f32(const float* __restrict__ in, float* __restrict__ out, int n) {
  int i = blockIdx.x * blockDim.x + threadIdx.x;
  if (i < n) out[i] = in[i];
}

// ---------------- RoPE folded into weight rows (angle indexed by HEAD, per reference quirk) ----
__global__ void rope_fold_w(const float* __restrict__ W, u16* __restrict__ out, int npair) {
  int idx = blockIdx.x * blockDim.x + threadIdx.x;
  int p  = idx >> 9;
  int c4 = (idx & 511) << 2;
  if (p >= npair) return;
  int h  = p >> 6;
  int ii = p & 63;
  float theta = __expf(-(float)ii * (9.210340371976184f / 64.0f));
  float s, c;
  __sincosf((float)h * theta, &s, &c);
  size_t r0 = (size_t)(2 * p) * 2048 + c4;
  size_t r1 = r0 + 2048;
  float4 a = *(const float4*)(W + r0);
  float4 b = *(const float4*)(W + r1);
  ushort4 o0, o1;
  o0.x = f2bf(a.x * c - b.x * s); o0.y = f2bf(a.y * c - b.y * s);
  o0.z = f2bf(a.z * c - b.z * s); o0.w = f2bf(a.w * c - b.w * s);
  o1.x = f2bf(b.x * c + a.x * s); o1.y = f2bf(b.y * c + a.y * s);
  o1.z = f2bf(b.z * c + a.z * s); o1.w = f2bf(b.w * c + a.w * s);
  *(ushort4*)(out + r0) = o0;
  *(ushort4*)(out + r1) = o1;
}

__global__ void rope_fold_b(const float* __restrict__ bin, float* __restrict__ bout, int npair) {
  int p = blockIdx.x * blockDim.x + threadIdx.x;
  if (p >= npair) return;
  int h = p >> 6, ii = p & 63;
  float theta = __expf(-(float)ii * (9.210340371976184f / 64.0f));
  float s, c;
  __sincosf((float)h * theta, &s, &c);
  float a = bin[2 * p], b = bin[2 * p + 1];
  bout[2 * p]     = a * c - b * s;
  bout[2 * p + 1] = b * c + a * s;
}

// ---------------- 8-wave deep-pipelined GEMM: C[M,N] = A[M,2048] @ W[N,2048]^T + bias ------
// BM=256, BK=64, 8 waves (2M x 4N), 4 phases per K-tile. A is TRIPLE-buffered (issued 2
// tiles ahead at phase 1 — covers the L2-miss A stream); B is double-buffered (issued 1
// tile ahead at phase 0 — W is L2-resident per XCD). Tile-end wait is s_waitcnt vmcnt(4)
// (A(t+2) stays in flight) + raw s_barrier — vmcnt NEVER drains to 0 in the main loop.
// Chunk-XOR LDS swizzle (phys_chunk = chunk ^ (row&7)) via pre-swizzled global source.
// MODE 0: fused QKV epilogue (BN=192); MODE 1: fp32 [M,2048] out (BN=128).
template<int BN, int MODE>
__global__ __launch_bounds__(512)
void gemm8(const u16* __restrict__ A, const u16* __restrict__ W,
           const float* __restrict__ bias, void* __restrict__ op0,
           void* __restrict__ op1, void* __restrict__ op2, const float qscale) {
  constexpr int NREP = BN / 64;            // n-frags per wave (3 or 2)
  constexpr int ASZ  = 256 * 64;           // A-tile u16 (32 KB)
  constexpr int BSZ  = BN * 64;            // B-tile u16
  constexpr int NB   = BSZ / 4096;         // B gloads per thread (3 or 2)
  constexpr int BB0  = 3 * ASZ;            // B region base (u16 idx)
  __shared__ __align__(16) u16 sm[3 * ASZ + 2 * BSZ];
  const int tid  = threadIdx.x;
  const int lane = tid & 63;
  const int wid  = tid >> 6;
  const int wr = wid >> 2, wc = wid & 3;
  const int m0 = blockIdx.y << 8;
  const int n0 = blockIdx.x * BN;
  const int K  = C_;
  const int fr = lane & 15, g = lane >> 4;

  // staging address precompute (pre-swizzled source chunk, linear LDS dest)
  const u16* srcA[4]; int dstA[4];
#pragma unroll
  for (int i = 0; i < 4; ++i) {
    const int idx = i * 512 + tid;
    const int row = idx >> 3, sch = (idx & 7) ^ (row & 7);
    srcA[i] = A + (size_t)(m0 + row) * K + sch * 8;
    dstA[i] = idx * 8;
  }
  const u16* srcB[NB]; int dstB[NB];
#pragma unroll
  for (int i = 0; i < NB; ++i) {
    const int idx = i * 512 + tid;
    const int row = idx >> 3, sch = (idx & 7) ^ (row & 7);
    srcB[i] = W + (size_t)(n0 + row) * K + sch * 8;
    dstB[i] = idx * 8;
  }
  // ds_read swizzled k-chunk offsets (row&7 == fr&7 for all frag rows)
  const int swz0 = ((g     ^ (fr & 7)) << 3);
  const int swz1 = (((4+g) ^ (fr & 7)) << 3);

  f32x4 acc[8][NREP] = {};

#define STAGE_A(buf, ko) {                                               \
  _Pragma("unroll")                                                      \
  for (int i = 0; i < 4; ++i)                                            \
    gload16(srcA[i] + (ko), sm + (buf) * ASZ + dstA[i]); }
#define STAGE_B(buf, ko) {                                               \
  _Pragma("unroll")                                                      \
  for (int i = 0; i < NB; ++i)                                           \
    gload16(srcB[i] + (ko), sm + BB0 + (buf) * BSZ + dstB[i]); }

  // prologue: A(0), B(0), A(1); wait leaves A(1) in flight (steady-state invariant)
  STAGE_A(0, 0)
  STAGE_B(0, 0)
  STAGE_A(1, 64)
  asm volatile("s_waitcnt vmcnt(4)" ::: "memory");
  __builtin_amdgcn_s_barrier();
  __builtin_amdgcn_sched_barrier(0);

#define LDA(MH, SWZ) {                                                   \
  _Pragma("unroll")                                                      \
  for (int mi = 0; mi < 4; ++mi) {                                       \
    const int row = wr * 128 + (MH) * 64 + mi * 16 + fr;                 \
    af[mi] = *(const bf16x8*)&sm[ard + row * 64 + (SWZ)];                \
  } }
#define LDB(BF, SWZ) {                                                   \
  _Pragma("unroll")                                                      \
  for (int ni = 0; ni < NREP; ++ni) {                                    \
    const int row = wc * (BN / 4) + ni * 16 + fr;                        \
    BF[ni] = *(const bf16x8*)&sm[brd + row * 64 + (SWZ)];                \
  } }
#define MM(MH, BF) {                                                     \
  __builtin_amdgcn_s_setprio(1);                                         \
  _Pragma("unroll")                                                      \
  for (int mi = 0; mi < 4; ++mi)                                         \
    _Pragma("unroll")                                                    \
    for (int ni = 0; ni < NREP; ++ni)                                    \
      acc[(MH) * 4 + mi][ni] = __builtin_amdgcn_mfma_f32_16x16x32_bf16(  \
          af[mi], BF[ni], acc[(MH) * 4 + mi][ni], 0, 0, 0);              \
  __builtin_amdgcn_s_setprio(0); }

  int a0 = 0;                                  // A buffer of tile t (t % 3)
  for (int t = 0; t < 32; ++t) {
    int a2 = a0 + 2; if (a2 >= 3) a2 -= 3;     // A buffer of tile t+2
    const int ard = a0 * ASZ;
    const int brd = BB0 + (t & 1) * BSZ;
    bf16x8 af[4], bfa[NREP], bfb[NREP];
    // ---- phase 0 (mh0, kc0): issue B(t+1)
    if (t < 31) {
      STAGE_B((t & 1) ^ 1, (t + 1) * 64)
      __builtin_amdgcn_sched_barrier(0);
    }
    LDA(0, swz0) LDB(bfa, swz0) MM(0, bfa)
    __builtin_amdgcn_s_barrier();
    // ---- phase 1 (mh1, kc0): issue A(t+2)
    if (t < 30) {
      STAGE_A(a2, (t + 2) * 64)
      __builtin_amdgcn_sched_barrier(0);
    }
    LDA(1, swz0) MM(1, bfa)
    __builtin_amdgcn_s_barrier();
    // ---- phase 2 (mh0, kc1)
    LDB(bfb, swz1) LDA(0, swz1) MM(0, bfb)
    __builtin_amdgcn_s_barrier();
    // ---- phase 3 (mh1, kc1); counted tile-end wait (never drains to 0 until tail)
    LDA(1, swz1) MM(1, bfb)
    if (t < 30)       asm volatile("s_waitcnt vmcnt(4)" ::: "memory");
    else if (t == 30) asm volatile("s_waitcnt vmcnt(0)" ::: "memory");
    if (t < 31) {
      __builtin_amdgcn_s_barrier();
      __builtin_amdgcn_sched_barrier(0);
    }
    a0 = a0 + 1; if (a0 == 3) a0 = 0;
  }
#undef LDA
#undef LDB
#undef MM
#undef STAGE_A
#undef STAGE_B

  // ---- epilogue
#pragma unroll
  for (int mh = 0; mh < 2; ++mh)
#pragma unroll
    for (int mi = 0; mi < 4; ++mi) {
      const int rg0 = m0 + wr * 128 + mh * 64 + mi * 16 + ((lane >> 4) << 2);
#pragma unroll
      for (int ni = 0; ni < NREP; ++ni) {
        const int cg = n0 + wc * (BN / 4) + ni * 16 + fr;
        const float bb = bias[cg];
#pragma unroll
        for (int r = 0; r < 4; ++r) {
          float v = acc[mh * 4 + mi][ni][r] + bb;
          const int rg = rg0 + r;
          if (MODE == 1) {
            ((float*)op0)[(size_t)rg * C_ + cg] = v;
          } else {
            const int b = rg >> 11, t = rg & (T_ - 1);
            if (cg < 2048) {
              const int h = cg >> 7, d = cg & 127;
              ((u16*)op0)[((((size_t)b * NH_ + h) * T_ + t) << 7) + d] = f2bf(v * qscale);
            } else if (cg < 2560) {
              const int c2 = cg - 2048, h = c2 >> 7, d = c2 & 127;
              ((u16*)op1)[((((size_t)b * NKV_ + h) * T_ + t) << 7) + d] = f2bf(v);
            } else {
              const int c2 = cg - 2560, h = c2 >> 7, d = c2 & 127;
              ((u16*)op2)[(((size_t)b * NKV_ + h) * HD_ + d) * T_ + t] = f2bf(v);
            }
          }
        }
      }
    }
}

// ---------------- causal GQA flash attention (4 warps x 32 q-rows, 32x32x16 MFMA) ------------
__device__ __forceinline__ void stage_kv(u16* dst, const u16* __restrict__ kg,
                                         const u16* __restrict__ vg, int lane, int w) {
#pragma unroll
  for (int r = 0; r < 4; ++r) {           // K: 64 rows x 16 chunks
    const int row = r * 16 + w * 4 + (lane >> 4);
    const int cg  = (lane & 15) ^ (row & 7);
    gload16(kg + (size_t)row * 128 + cg * 8, dst + row * 128 + (lane & 15) * 8);
  }
#pragma unroll
  for (int r = 0; r < 4; ++r) {           // Vt: 128 rows x 8 chunks
    const int row = r * 32 + w * 8 + (lane >> 3);
    const int cg  = (lane & 7) ^ (row & 7);
    gload16(vg + (size_t)row * T_ + cg * 8, dst + 8192 + row * 64 + (lane & 7) * 8);
  }
}

__global__ __launch_bounds__(256, 2)
void attn2(const u16* __restrict__ q, const u16* __restrict__ k,
           const u16* __restrict__ vt, u16* __restrict__ y) {
  __shared__ __align__(16) u16 sm[32768];
  const int tid  = threadIdx.x;
  const int lane = tid & 63;
  const int w    = tid >> 6;
  const int hi   = lane >> 5;
  const int l5   = lane & 31;
  const int h = blockIdx.y;
  const int b = blockIdx.z;
  // complementary pairing: co-resident (x,y,0)/(x,y,1) get qt summing to 15 -> uniform CU load
  const int qt = b ? (int)blockIdx.x : (15 - (int)blockIdx.x);
  const int q0  = qt << 7;
  const int q0w = q0 + w * 32;
  const int nkv = 2 * qt + 2;
  const size_t qbase = (((size_t)b * NH_ + h) * T_ + q0) * HD_;
  const size_t kbase = ((size_t)b * NKV_ + (h >> 2)) * (size_t)T_ * HD_;
  const size_t vbase = ((size_t)b * NKV_ + (h >> 2)) * (size_t)HD_ * T_;

  // ---- stage Q [128][128] (swizzled) into sm[0..16384)
#pragma unroll
  for (int r = 0; r < 8; ++r) {
    const int row = r * 16 + w * 4 + (lane >> 4);
    const int cg  = (lane & 15) ^ (row & 7);
    gload16(q + qbase + (size_t)row * 128 + cg * 8, sm + row * 128 + (lane & 15) * 8);
  }
  __syncthreads();
  bf16x8 qf[8];
  {
    const int row = w * 32 + l5;
#pragma unroll
    for (int kd = 0; kd < 8; ++kd)
      qf[kd] = *(const bf16x8*)&sm[row * 128 + ((((kd << 1) | hi) ^ (row & 7)) << 3)];
  }
  __syncthreads();
  stage_kv(sm, k + kbase, vt + vbase, lane, w);

  f32x16 o[4] = {};
  float m = -1e30f, l = 0.f;

  for (int kv = 0; kv < nkv; ++kv) {
    __syncthreads();               // staging of current buf complete (vmcnt(0)+barrier)
    const int buf = kv & 1;
    if (kv + 1 < nkv)
      stage_kv(sm + ((buf ^ 1) << 14),
               k + kbase + ((size_t)(kv + 1) << 6) * 128,
               vt + vbase + ((kv + 1) << 6), lane, w);

    if ((kv << 6) <= q0w + 31) {
      const u16* Ks = sm + (buf << 14);
      const u16* Vs = Ks + 8192;

      // ---- S^T = K @ Q^T : lane holds S^T[k=crow(r,hi)][q=l5]
      f32x16 st[2] = {};
      __builtin_amdgcn_s_setprio(1);
#pragma unroll
      for (int kt = 0; kt < 2; ++kt) {
        const int krow = kt * 32 + l5;
#pragma unroll
        for (int kd = 0; kd < 8; ++kd) {
          bf16x8 ka = *(const bf16x8*)&Ks[krow * 128 + ((((kd << 1) | hi) ^ (l5 & 7)) << 3)];
          st[kt] = __builtin_amdgcn_mfma_f32_32x32x16_bf16(ka, qf[kd], st[kt], 0, 0, 0);
        }
      }
      __builtin_amdgcn_s_setprio(0);

      // ---- causal mask (diagonal tiles only)
      if ((kv << 6) + 63 > q0w) {
        const int qg = q0w + l5;
#pragma unroll
        for (int kt = 0; kt < 2; ++kt)
#pragma unroll
          for (int r = 0; r < 16; ++r) {
            const int kg = (kv << 6) + kt * 32 + (r & 3) + ((r >> 2) << 3) + (hi << 2);
            if (kg > qg) st[kt][r] = -3.0e38f;
          }
      }

      // ---- online softmax (log2 domain; scale folded into Q)
      float pmax = -3.0e38f;
#pragma unroll
      for (int kt = 0; kt < 2; ++kt)
#pragma unroll
        for (int r = 0; r < 16; ++r) pmax = fmaxf(pmax, st[kt][r]);
      pmax = fmaxf(pmax, __shfl_xor(pmax, 32));
      if (!__all(pmax - m <= 8.0f)) {        // defer-max (T13)
        const float mn = fmaxf(m, pmax);
        const float f = fexp2(m - mn);
        m = mn;
        l *= f;
#pragma unroll
        for (int r = 0; r < 16; ++r) {
          const float fr = __shfl(f, (r & 3) + ((r >> 2) << 3) + (hi << 2));
          o[0][r] *= fr; o[1][r] *= fr; o[2][r] *= fr; o[3][r] *= fr;
        }
      }

      // ---- P = exp2(S^T - m), pack to PV A-fragments in-register, PV MFMAs
      float rs = 0.f;
#pragma unroll
      for (int kt = 0; kt < 2; ++kt) {
#pragma unroll
        for (int s = 0; s < 2; ++s) {
          float e0 = fexp2(st[kt][8 * s + 0] - m), e1 = fexp2(st[kt][8 * s + 1] - m);
          float e2 = fexp2(st[kt][8 * s + 2] - m), e3 = fexp2(st[kt][8 * s + 3] - m);
          float e4 = fexp2(st[kt][8 * s + 4] - m), e5 = fexp2(st[kt][8 * s + 5] - m);
          float e6 = fexp2(st[kt][8 * s + 6] - m), e7 = fexp2(st[kt][8 * s + 7] - m);
          rs += ((e0 + e1) + (e2 + e3)) + ((e4 + e5) + (e6 + e7));
          const unsigned wL0 = cvtpk(e0, e1), wL1 = cvtpk(e2, e3);
          const unsigned wH0 = cvtpk(e4, e5), wH1 = cvtpk(e6, e7);
          const unsigned s0 = hi ? wL0 : wH0, s1 = hi ? wL1 : wH1;
          const unsigned r0 = __shfl_xor(s0, 32), r1 = __shfl_xor(s1, 32);
          u32x4 fw;
          fw.x = hi ? r0 : wL0; fw.y = hi ? r1 : wL1;
          fw.z = hi ? wH0 : r0; fw.w = hi ? wH1 : r1;
          const bf16x8 pa = __builtin_bit_cast(bf16x8, fw);
          const int ch = (((kt * 2 + s) << 1) | hi) ^ (l5 & 7);
          __builtin_amdgcn_s_setprio(1);
#pragma unroll
          for (int ds = 0; ds < 4; ++ds) {
            const int vrow = ds * 32 + l5;
            bf16x8 vb = *(const bf16x8*)&Vs[vrow * 64 + (ch << 3)];
            o[ds] = __builtin_amdgcn_mfma_f32_32x32x16_bf16(pa, vb, o[ds], 0, 0, 0);
          }
          __builtin_amdgcn_s_setprio(0);
        }
      }
      rs += __shfl_xor(rs, 32);
      l += rs;
    }
  }

  // ---- epilogue: O /= l, write y[b, q, h*128 + d]
  const float linv = 1.0f / l;
#pragma unroll
  for (int r = 0; r < 16; ++r) {
    const int crow = (r & 3) + ((r >> 2) << 3) + (hi << 2);
    const float lf = __shfl(linv, crow);
    const int qg = q0w + crow;
    const size_t rowoff = (((size_t)(b << 11) + qg) << 11) + (h << 7) + l5;
#pragma unroll
    for (int ds = 0; ds < 4; ++ds)
      y[rowoff + ds * 32] = f2bf(o[ds][r] * lf);
  }
}

// ---------------- launch ----------------
extern "C" void kernel_launch(void* const* d_in, const int* in_sizes, int n_in,
                              void* d_out, int out_size, void* d_ws, size_t ws_size,
                              hipStream_t stream) {
  (void)in_sizes; (void)n_in; (void)out_size; (void)ws_size;
  const float* x    = (const float*)d_in[0];
  const float* wq_w = (const float*)d_in[1];
  const float* wq_b = (const float*)d_in[2];
  const float* wk_w = (const float*)d_in[3];
  const float* wk_b = (const float*)d_in[4];
  const float* wv_w = (const float*)d_in[5];
  const float* wv_b = (const float*)d_in[6];
  const float* cp_w = (const float*)d_in[7];
  const float* cp_b = (const float*)d_in[8];

  char* ws = (char*)d_ws;
  u16* xb  = (u16*)ws;  ws += (size_t)M_ * C_ * 2;        // x bf16; later reused as y
  u16* wqr = (u16*)ws;  ws += (size_t)C_ * C_ * 2;        // rotated wq (rows 0..2047 of Wcat)
  u16* wkr = (u16*)ws;  ws += (size_t)512 * C_ * 2;       // rotated wk (rows 2048..2559)
  u16* wvb = (u16*)ws;  ws += (size_t)512 * C_ * 2;       // wv        (rows 2560..3071)
  u16* cpb = (u16*)ws;  ws += (size_t)C_ * C_ * 2;
  u16* qb  = (u16*)ws;  ws += (size_t)M_ * C_ * 2;
  u16* kb  = (u16*)ws;  ws += (size_t)M_ * 512 * 2;
  u16* vtb = (u16*)ws;  ws += (size_t)M_ * 512 * 2;
  float* bqkv = (float*)ws; ws += 3072 * 4;               // concat bias (fp32)
  u16* yb = xb;

  cvt_bf16<<<8192, 256, 0, stream>>>((const float4*)x,    (ushort4*)xb,  2097152);
  cvt_bf16<<<1024, 256, 0, stream>>>((const float4*)wv_w, (ushort4*)wvb, 262144);
  cvt_bf16<<<4096, 256, 0, stream>>>((const float4*)cp_w, (ushort4*)cpb, 1048576);
  rope_fold_w<<<2048, 256, 0, stream>>>(wq_w, wqr, 1024);
  rope_fold_w<<<512,  256, 0, stream>>>(wk_w, wkr, 256);
  rope_fold_b<<<4, 256, 0, stream>>>(wq_b, bqkv, 1024);
  rope_fold_b<<<1, 256, 0, stream>>>(wk_b, bqkv + 2048, 256);
  copy_f32<<<2, 256, 0, stream>>>(wv_b, bqkv + 2560, 512);

  // Q pre-scaled by log2e / sqrt(HD) so attention softmax runs in exp2 domain
  const float qscale = 0.08838834764831843f * 1.4426950408889634f;
  gemm8<192, 0><<<dim3(16, 16), 512, 0, stream>>>(xb, wqr, bqkv, qb, kb, vtb, qscale);

  attn2<<<dim3(16, 16, 2), 256, 0, stream>>>(qb, kb, vtb, yb);

  gemm8<128, 1><<<dim3(16, 16), 512, 0, stream>>>(yb, cpb, cp_b, (float*)d_out,
                                                  nullptr, nullptr, 1.0f);
}